// Round 11
// baseline (307.797 us; speedup 1.0000x reference)
//
#include <hip/hip_runtime.h>
#include <hip/hip_bf16.h>

typedef short short8 __attribute__((ext_vector_type(8)));
typedef float f32x4 __attribute__((ext_vector_type(4)));
typedef unsigned int uint4v __attribute__((ext_vector_type(4)));

__device__ __forceinline__ short f2bf(float f) {
  unsigned u = __builtin_bit_cast(unsigned, f);
  u += 0x7fffu + ((u >> 16) & 1u);          // RNE
  return (short)(u >> 16);
}
__device__ __forceinline__ float bf2f(short s) {
  unsigned u = ((unsigned)(unsigned short)s) << 16;
  return __builtin_bit_cast(float, u);
}
__device__ __forceinline__ unsigned pk2(float a, float b) {
  __hip_bfloat162 h = __float22bfloat162_rn(float2{a, b});
  unsigned u;
  __builtin_memcpy(&u, &h, 4);
  return u;
}
__device__ __forceinline__ void gl_lds16(const void* g, void* l) {
  __builtin_amdgcn_global_load_lds(
      (const __attribute__((address_space(1))) unsigned int*)g,
      (__attribute__((address_space(3))) unsigned int*)l, 16, 0, 0);
}
// 8 fp32 (2 f32x4) -> short8 bf16 fragment
__device__ __forceinline__ short8 cvt8(f32x4 a, f32x4 b) {
  uint4v u;
  u[0] = pk2(a[0], a[1]); u[1] = pk2(a[2], a[3]);
  u[2] = pk2(b[0], b[1]); u[3] = pk2(b[2], b[3]);
  return __builtin_bit_cast(short8, u);
}

// ---------------- W transpose + bf16: Wt[z][n][k], z=0:WK z=1:WV ------------
__global__ __launch_bounds__(256) void wt_kernel(
    const float* __restrict__ WK, const float* __restrict__ WV,
    short* __restrict__ Wt)
{
  const int z = blockIdx.z;
  const float* W = (z == 0) ? WK : WV;
  short* o = Wt + (size_t)z * 512 * 512;
  __shared__ short t[64][65];
  const int k0 = blockIdx.y * 64, n0 = blockIdx.x * 64;
  const int c = threadIdx.x & 63, rb = threadIdx.x >> 6;
#pragma unroll
  for (int p = 0; p < 16; ++p) {
    const int kk = p * 4 + rb;
    t[kk][c] = f2bf(W[(size_t)(k0 + kk) * 512 + n0 + c]);
  }
  __syncthreads();
#pragma unroll
  for (int p = 0; p < 16; ++p) {
    const int nn = p * 4 + rb;
    o[(size_t)(n0 + nn) * 512 + k0 + c] = t[c][nn];
  }
}

// ======== A-direct GEMM core: 128x128 tile, A fp32 from global, B gl_lds ====
// proj: K/V projections. grid 2048 = 2z x 256mt x 4ct
__global__ __launch_bounds__(256) void proj_kernel(
    const float* __restrict__ Kin, const float* __restrict__ Vin,
    const short* __restrict__ Wt,
    const float* __restrict__ bK, const float* __restrict__ bV,
    short* __restrict__ kp, short* __restrict__ vp)
{
  const int phys = blockIdx.x;
  const int log_ = (phys & 7) * 256 + (phys >> 3);   // 2048 = 8*256 bijective
  const int z = log_ >> 10;
  const int rem = log_ & 1023;
  const int row0 = (rem >> 2) * 128;
  const int col0 = (rem & 3) * 128;

  const float* X    = z ? Vin : Kin;
  const short* Bsrc = Wt + (size_t)z * 512 * 512;
  const float* bias = z ? bV : bK;
  short* dst        = z ? vp : kp;

  __shared__ short b_lds[2][128 * 32];   // 16 KB total

  const int tid = threadIdx.x;
  const int lane = tid & 63, wv = tid >> 6;
  const int wr = wv >> 1, wc = wv & 1;
  const int fr = lane & 15, fg = lane >> 4;

  // B staging (R9-proven): wave wv stages rows wv*16..+15 of each 64-half
  const int srow = wv * 16 + (lane >> 2);
  const int sswz = ((lane & 3) ^ (srow & 3)) * 8;    // pre-swizzled source k
  const int sdst = (wv * 16) * 32 + lane * 8;        // linear LDS dest
  const int soff = (fg ^ (fr & 3)) * 8;              // swizzled frag-read slot

  // A direct: per mi, row-base pointer at this lane's (row, fg-seg)
  const float* arow[4];
#pragma unroll
  for (int mi = 0; mi < 4; ++mi)
    arow[mi] = X + (size_t)(row0 + wr * 64 + mi * 16 + fr) * 512 + fg * 8;

  f32x4 acc[4][4];
#pragma unroll
  for (int i = 0; i < 4; ++i)
#pragma unroll
    for (int j = 0; j < 4; ++j) acc[i][j] = (f32x4){0.f, 0.f, 0.f, 0.f};

  f32x4 va[4][2];
#pragma unroll
  for (int mi = 0; mi < 4; ++mi) {       // A(0)
    va[mi][0] = *(const f32x4*)(arow[mi]);
    va[mi][1] = *(const f32x4*)(arow[mi] + 4);
  }
  // B(0) -> buf 0
#pragma unroll
  for (int i = 0; i < 2; ++i)
    gl_lds16(Bsrc + (size_t)(col0 + i * 64 + srow) * 512 + sswz,
             &b_lds[0][(i * 64) * 32 + sdst]);
  __syncthreads();

  for (int t = 0; t < 16; ++t) {
    short8 af[4];
#pragma unroll
    for (int mi = 0; mi < 4; ++mi) af[mi] = cvt8(va[mi][0], va[mi][1]);
    short8 bfv[4];
    const short* bc = b_lds[t & 1];
#pragma unroll
    for (int ni = 0; ni < 4; ++ni)
      bfv[ni] = *(const short8*)&bc[(wc * 64 + ni * 16 + fr) * 32 + soff];
    if (t < 15) {                        // prefetch t+1 (B->LDS, A->regs)
      const int k1 = (t + 1) * 32;
      short* bn = b_lds[(t + 1) & 1];
#pragma unroll
      for (int i = 0; i < 2; ++i)
        gl_lds16(Bsrc + (size_t)(col0 + i * 64 + srow) * 512 + k1 + sswz,
                 &bn[(i * 64) * 32 + sdst]);
#pragma unroll
      for (int mi = 0; mi < 4; ++mi) {
        va[mi][0] = *(const f32x4*)(arow[mi] + k1);
        va[mi][1] = *(const f32x4*)(arow[mi] + k1 + 4);
      }
    }
    __builtin_amdgcn_s_setprio(1);
#pragma unroll
    for (int mi = 0; mi < 4; ++mi)
#pragma unroll
      for (int ni = 0; ni < 4; ++ni)
        acc[mi][ni] = __builtin_amdgcn_mfma_f32_16x16x32_bf16(af[mi], bfv[ni], acc[mi][ni], 0, 0, 0);
    __builtin_amdgcn_s_setprio(0);
    __syncthreads();
  }

#pragma unroll
  for (int ni = 0; ni < 4; ++ni) {
    const int gc = col0 + wc * 64 + ni * 16 + fr;
    const float bv = bias[gc];
#pragma unroll
    for (int mi = 0; mi < 4; ++mi) {
#pragma unroll
      for (int r = 0; r < 4; ++r) {
        const int gr = row0 + wr * 64 + mi * 16 + fg * 4 + r;
        dst[(size_t)gr * 512 + gc] = f2bf(acc[mi][ni][r] + bv);
      }
    }
  }
}

// ---------------- LN + ktv accumulation (unchanged) -------------------------
#define SC 256
#define TP 264

__global__ __launch_bounds__(256) void ktv_kernel(
    const short* __restrict__ kp, const short* __restrict__ vp,
    const float* __restrict__ pos,
    const float* __restrict__ lnwK, const float* __restrict__ lnbK,
    const float* __restrict__ lnwV, const float* __restrict__ lnbV,
    float* __restrict__ ktv)
{
  const int nh = blockIdx.y;
  const int n = nh >> 4, h = nh & 15;
  const int s0 = blockIdx.x * SC;
  const int tid = threadIdx.x;

  __shared__ short klds[48 * TP];
  __shared__ short vlds[48 * TP];
  __shared__ float lw[2][32], lb[2][32];

  if (tid < 32) {
    lw[0][tid] = lnwK[h * 32 + tid]; lb[0][tid] = lnbK[h * 32 + tid];
    lw[1][tid] = lnwV[h * 32 + tid]; lb[1][tid] = lnbV[h * 32 + tid];
  }
  __syncthreads();

  const size_t rowix = (size_t)n * 8192 + (s0 + tid);
  {
    const short8* src = (const short8*)(kp + rowix * 512 + h * 32);
    short8 r0 = src[0], r1 = src[1], r2 = src[2], r3 = src[3];
    float x[32];
#pragma unroll
    for (int i = 0; i < 8; ++i) { x[i] = bf2f(r0[i]); x[8+i] = bf2f(r1[i]); x[16+i] = bf2f(r2[i]); x[24+i] = bf2f(r3[i]); }
    float mu = 0.f;
#pragma unroll
    for (int i = 0; i < 32; ++i) mu += x[i];
    mu *= (1.f / 32.f);
    float var = 0.f;
#pragma unroll
    for (int i = 0; i < 32; ++i) { float d = x[i] - mu; var += d * d; }
    var *= (1.f / 32.f);
    const float rstd = rsqrtf(var + 1e-5f);
#pragma unroll
    for (int d = 0; d < 32; ++d)
      klds[d * TP + tid] = f2bf((x[d] - mu) * rstd * lw[0][d] + lb[0][d]);
  }
  {
    const short8* src = (const short8*)(vp + rowix * 512 + h * 32);
    short8 r0 = src[0], r1 = src[1], r2 = src[2], r3 = src[3];
    float x[32];
#pragma unroll
    for (int i = 0; i < 8; ++i) { x[i] = bf2f(r0[i]); x[8+i] = bf2f(r1[i]); x[16+i] = bf2f(r2[i]); x[24+i] = bf2f(r3[i]); }
    float mu = 0.f;
#pragma unroll
    for (int i = 0; i < 32; ++i) mu += x[i];
    mu *= (1.f / 32.f);
    float var = 0.f;
#pragma unroll
    for (int i = 0; i < 32; ++i) { float d = x[i] - mu; var += d * d; }
    var *= (1.f / 32.f);
    const float rstd = rsqrtf(var + 1e-5f);
#pragma unroll
    for (int d = 0; d < 32; ++d)
      vlds[d * TP + tid] = f2bf((x[d] - mu) * rstd * lw[1][d] + lb[1][d]);
  }
  {
    const short p0 = f2bf(pos[rowix * 2]);
    const short p1 = f2bf(pos[rowix * 2 + 1]);
    klds[32 * TP + tid] = p0; klds[33 * TP + tid] = p1;
    vlds[32 * TP + tid] = p0; vlds[33 * TP + tid] = p1;
  }
  __syncthreads();

  const int wv = tid >> 6, lane = tid & 63;
  if (wv < 3) {
    const int fr = lane & 15, fg = lane >> 4;
    f32x4 acc[3];
#pragma unroll
    for (int i = 0; i < 3; ++i) acc[i] = (f32x4){0.f, 0.f, 0.f, 0.f};
    for (int kk = 0; kk < SC; kk += 32) {
      short8 a = *(const short8*)&klds[(wv * 16 + fr) * TP + kk + fg * 8];
#pragma unroll
      for (int ni = 0; ni < 3; ++ni) {
        short8 b = *(const short8*)&vlds[(ni * 16 + fr) * TP + kk + fg * 8];
        acc[ni] = __builtin_amdgcn_mfma_f32_16x16x32_bf16(a, b, acc[ni], 0, 0, 0);
      }
    }
#pragma unroll
    for (int ni = 0; ni < 3; ++ni) {
      const int ei = ni * 16 + fr;
      if (ei < 34) {
        const int er = (ei < 32) ? ei + 2 : ei - 32;
#pragma unroll
        for (int r = 0; r < 4; ++r) {
          const int di = wv * 16 + fg * 4 + r;
          if (di < 34) {
            const int dr = (di < 32) ? di + 2 : di - 32;
            atomicAdd(&ktv[((size_t)nh * 34 + dr) * 34 + er], acc[ni][r]);
          }
        }
      }
    }
  }
}

// ---- S-build (64x4): St[n][o][m] fp32 + Pp3 accumulators -------------------
__global__ __launch_bounds__(256) void sbuild_kernel(
    const float* __restrict__ ktv, const float* __restrict__ fcW,
    const float* __restrict__ bQ, float* __restrict__ St, float* __restrict__ Pp3)
{
  const int nh = blockIdx.x;
  const int n = nh >> 4, h = nh & 15;
  const int jq = blockIdx.y;
  __shared__ float g[34 * 34];
  __shared__ float bq8[8];
  for (int i = threadIdx.x; i < 34 * 34; i += 256)
    g[i] = ktv[(size_t)nh * 34 * 34 + i] * (1.f / 8192.f);
  if (threadIdx.x < 8) bq8[threadIdx.x] = bQ[h * 32 + jq * 8 + threadIdx.x];
  __syncthreads();

  for (int o = threadIdx.x; o < 512; o += 256) {
    float wcol[34];
#pragma unroll
    for (int e = 0; e < 34; ++e) wcol[e] = fcW[(size_t)o * 544 + h * 34 + e];
    float rv = 0.f;
    float* srow = St + ((size_t)n * 512 + o) * 512 + h * 32 + jq * 8;
#pragma unroll
    for (int jj = 0; jj < 8; ++jj) {
      const int j = jq * 8 + jj;
      float s = 0.f;
#pragma unroll
      for (int e = 0; e < 34; ++e) s += g[(j + 2) * 34 + e] * wcol[e];
      srow[jj] = s;
      rv += bq8[jj] * s;
    }
    atomicAdd(&Pp3[((size_t)n * 3 + 2) * 512 + o], rv);
    if (jq == 0) {
      float p0 = 0.f, p1 = 0.f;
#pragma unroll
      for (int e = 0; e < 34; ++e) { p0 += g[e] * wcol[e]; p1 += g[34 + e] * wcol[e]; }
      atomicAdd(&Pp3[((size_t)n * 3 + 0) * 512 + o], p0);
      atomicAdd(&Pp3[((size_t)n * 3 + 1) * 512 + o], p1);
    }
  }
}

// ---- C-build: Ct[n][o][k] = sum_m St[n][o][m] * WQ[k][m], bf16 out ---------
__global__ __launch_bounds__(256) void cbuild_kernel(
    const float* __restrict__ St, const float* __restrict__ WQ,
    short* __restrict__ Ct)
{
  const int n = blockIdx.z;
  const int row0 = blockIdx.y * 128;   // o
  const int col0 = blockIdx.x * 128;   // k
  const float* A = St + (size_t)n * 512 * 512;
  const float* B = WQ;

  __shared__ short a_lds[128 * 32];
  __shared__ short b_lds2[128 * 32];

  const int tid = threadIdx.x;
  const int lane = tid & 63, wv = tid >> 6;
  const int wr = wv >> 1, wc = wv & 1;
  const int fr = lane & 15, fg = lane >> 4;
  const int ar = tid >> 1, ak = (tid & 1) * 16;

  f32x4 acc[4][4];
#pragma unroll
  for (int i = 0; i < 4; ++i)
#pragma unroll
    for (int j = 0; j < 4; ++j) acc[i][j] = (f32x4){0.f, 0.f, 0.f, 0.f};

  for (int k0 = 0; k0 < 512; k0 += 32) {
    __syncthreads();
    {
      const f32x4* ap = (const f32x4*)(A + (size_t)(row0 + ar) * 512 + k0 + ak);
      f32x4 f0 = ap[0], f1 = ap[1], f2 = ap[2], f3 = ap[3];
      uint4v s0, s1;
      s0[0] = pk2(f0[0], f0[1]); s0[1] = pk2(f0[2], f0[3]);
      s0[2] = pk2(f1[0], f1[1]); s0[3] = pk2(f1[2], f1[3]);
      s1[0] = pk2(f2[0], f2[1]); s1[1] = pk2(f2[2], f2[3]);
      s1[2] = pk2(f3[0], f3[1]); s1[3] = pk2(f3[2], f3[3]);
      *(uint4v*)&a_lds[ar * 32 + ak] = s0;
      *(uint4v*)&a_lds[ar * 32 + ak + 8] = s1;
      const f32x4* bp = (const f32x4*)(B + (size_t)(col0 + ar) * 512 + k0 + ak);
      f32x4 g0 = bp[0], g1 = bp[1], g2 = bp[2], g3 = bp[3];
      s0[0] = pk2(g0[0], g0[1]); s0[1] = pk2(g0[2], g0[3]);
      s0[2] = pk2(g1[0], g1[1]); s0[3] = pk2(g1[2], g1[3]);
      s1[0] = pk2(g2[0], g2[1]); s1[1] = pk2(g2[2], g2[3]);
      s1[2] = pk2(g3[0], g3[1]); s1[3] = pk2(g3[2], g3[3]);
      *(uint4v*)&b_lds2[ar * 32 + ak] = s0;
      *(uint4v*)&b_lds2[ar * 32 + ak + 8] = s1;
    }
    __syncthreads();

    short8 af[4], bfr[4];
#pragma unroll
    for (int mi = 0; mi < 4; ++mi)
      af[mi] = *(const short8*)&a_lds[(wr * 64 + mi * 16 + fr) * 32 + fg * 8];
#pragma unroll
    for (int ni = 0; ni < 4; ++ni)
      bfr[ni] = *(const short8*)&b_lds2[(wc * 64 + ni * 16 + fr) * 32 + fg * 8];
#pragma unroll
    for (int mi = 0; mi < 4; ++mi)
#pragma unroll
      for (int ni = 0; ni < 4; ++ni)
        acc[mi][ni] = __builtin_amdgcn_mfma_f32_16x16x32_bf16(af[mi], bfr[ni], acc[mi][ni], 0, 0, 0);
  }

#pragma unroll
  for (int ni = 0; ni < 4; ++ni) {
    const int gc = col0 + wc * 64 + ni * 16 + fr;
#pragma unroll
    for (int mi = 0; mi < 4; ++mi)
#pragma unroll
      for (int r = 0; r < 4; ++r) {
        const int gr = row0 + wr * 64 + mi * 16 + fg * 4 + r;
        Ct[((size_t)n * 512 + gr) * 512 + gc] = f2bf(acc[mi][ni][r]);
      }
  }
}

// ======== fuse: out[n] = Q[n] @ Ct[n]^T + pos terms; A-direct core ==========
// grid 1024 = 4n x 64mt x 4ct
__global__ __launch_bounds__(256) void fuse_kernel(
    const float* __restrict__ Q, const short* __restrict__ Ct,
    const float* __restrict__ pos, const float* __restrict__ Pp3,
    const float* __restrict__ fcb, float* __restrict__ out)
{
  const int phys = blockIdx.x;
  const int log_ = (phys & 7) * 128 + (phys >> 3);   // 1024 = 8*128
  const int n = log_ >> 8;
  const int rem = log_ & 255;
  const int row0 = (rem >> 2) * 128;
  const int col0 = (rem & 3) * 128;

  const float* X    = Q + (size_t)n * 8192 * 512;
  const short* Bsrc = Ct + (size_t)n * 512 * 512;
  float* dstf       = out + (size_t)n * 8192 * 512;
  const float* posn = pos + (size_t)n * 8192 * 2;

  __shared__ short b_lds[2][128 * 32];

  const int tid = threadIdx.x;
  const int lane = tid & 63, wv = tid >> 6;
  const int wr = wv >> 1, wc = wv & 1;
  const int fr = lane & 15, fg = lane >> 4;

  const int srow = wv * 16 + (lane >> 2);
  const int sswz = ((lane & 3) ^ (srow & 3)) * 8;
  const int sdst = (wv * 16) * 32 + lane * 8;
  const int soff = (fg ^ (fr & 3)) * 8;

  const float* arow[4];
#pragma unroll
  for (int mi = 0; mi < 4; ++mi)
    arow[mi] = X + (size_t)(row0 + wr * 64 + mi * 16 + fr) * 512 + fg * 8;

  f32x4 acc[4][4];
#pragma unroll
  for (int i = 0; i < 4; ++i)
#pragma unroll
    for (int j = 0; j < 4; ++j) acc[i][j] = (f32x4){0.f, 0.f, 0.f, 0.f};

  f32x4 va[4][2];
#pragma unroll
  for (int mi = 0; mi < 4; ++mi) {
    va[mi][0] = *(const f32x4*)(arow[mi]);
    va[mi][1] = *(const f32x4*)(arow[mi] + 4);
  }
#pragma unroll
  for (int i = 0; i < 2; ++i)
    gl_lds16(Bsrc + (size_t)(col0 + i * 64 + srow) * 512 + sswz,
             &b_lds[0][(i * 64) * 32 + sdst]);
  __syncthreads();

  for (int t = 0; t < 16; ++t) {
    short8 af[4];
#pragma unroll
    for (int mi = 0; mi < 4; ++mi) af[mi] = cvt8(va[mi][0], va[mi][1]);
    short8 bfv[4];
    const short* bc = b_lds[t & 1];
#pragma unroll
    for (int ni = 0; ni < 4; ++ni)
      bfv[ni] = *(const short8*)&bc[(wc * 64 + ni * 16 + fr) * 32 + soff];
    if (t < 15) {
      const int k1 = (t + 1) * 32;
      short* bn = b_lds[(t + 1) & 1];
#pragma unroll
      for (int i = 0; i < 2; ++i)
        gl_lds16(Bsrc + (size_t)(col0 + i * 64 + srow) * 512 + k1 + sswz,
                 &bn[(i * 64) * 32 + sdst]);
#pragma unroll
      for (int mi = 0; mi < 4; ++mi) {
        va[mi][0] = *(const f32x4*)(arow[mi] + k1);
        va[mi][1] = *(const f32x4*)(arow[mi] + k1 + 4);
      }
    }
    __builtin_amdgcn_s_setprio(1);
#pragma unroll
    for (int mi = 0; mi < 4; ++mi)
#pragma unroll
      for (int ni = 0; ni < 4; ++ni)
        acc[mi][ni] = __builtin_amdgcn_mfma_f32_16x16x32_bf16(af[mi], bfv[ni], acc[mi][ni], 0, 0, 0);
    __builtin_amdgcn_s_setprio(0);
    __syncthreads();
  }

  float pp0[4], pp1[4], rv[4];
#pragma unroll
  for (int ni = 0; ni < 4; ++ni) {
    const int gc = col0 + wc * 64 + ni * 16 + fr;
    pp0[ni] = Pp3[((size_t)n * 3 + 0) * 512 + gc];
    pp1[ni] = Pp3[((size_t)n * 3 + 1) * 512 + gc];
    rv[ni]  = Pp3[((size_t)n * 3 + 2) * 512 + gc] + fcb[gc];
  }
#pragma unroll
  for (int mi = 0; mi < 4; ++mi) {
#pragma unroll
    for (int r = 0; r < 4; ++r) {
      const int gr = row0 + wr * 64 + mi * 16 + fg * 4 + r;
      const float q0 = posn[(size_t)gr * 2];
      const float q1 = posn[(size_t)gr * 2 + 1];
#pragma unroll
      for (int ni = 0; ni < 4; ++ni) {
        const int gc = col0 + wc * 64 + ni * 16 + fr;
        dstf[(size_t)gr * 512 + gc] =
            acc[mi][ni][r] + pp0[ni] * q0 + pp1[ni] * q1 + rv[ni];
      }
    }
  }
}

// ---------------------------------------------------------------------------
extern "C" void kernel_launch(void* const* d_in, const int* in_sizes, int n_in,
                              void* d_out, int out_size, void* d_ws, size_t ws_size,
                              hipStream_t stream) {
  const float* Q    = (const float*)d_in[0];
  const float* Kin  = (const float*)d_in[1];
  const float* Vin  = (const float*)d_in[2];
  const float* pos  = (const float*)d_in[3];
  const float* WQ   = (const float*)d_in[4];
  const float* WK   = (const float*)d_in[5];
  const float* WV   = (const float*)d_in[6];
  const float* bQ   = (const float*)d_in[7];
  const float* bK   = (const float*)d_in[8];
  const float* bV   = (const float*)d_in[9];
  const float* lnwK = (const float*)d_in[10];
  const float* lnbK = (const float*)d_in[11];
  const float* lnwV = (const float*)d_in[12];
  const float* lnbV = (const float*)d_in[13];
  const float* fcW  = (const float*)d_in[14];
  const float* fcb  = (const float*)d_in[15];

  char* ws = (char*)d_ws;
  const size_t KP_B  = (size_t)4 * 8192 * 512 * 2;   // 33,554,432
  const size_t KTV_B = (size_t)64 * 34 * 34 * 4;     //    295,936
  const size_t ST_B  = (size_t)4 * 512 * 512 * 4;    //  4,194,304
  const size_t CT_B  = (size_t)4 * 512 * 512 * 2;    //  2,097,152
  const size_t WT_B  = (size_t)2 * 512 * 512 * 2;    //  1,048,576
  const size_t PP_B  = (size_t)4 * 3 * 512 * 4;      //     24,576
  short* kp  = (short*)ws;
  short* vp  = (short*)(ws + KP_B);
  float* ktv = (float*)(ws + 2 * KP_B);
  float* St  = (float*)(ws + 2 * KP_B + KTV_B);
  short* Ct  = (short*)(ws + 2 * KP_B + KTV_B + ST_B);
  short* Wt  = (short*)(ws + 2 * KP_B + KTV_B + ST_B + CT_B);
  float* Pp3 = (float*)(ws + 2 * KP_B + KTV_B + ST_B + CT_B + WT_B);

  (void)hipMemsetAsync(ktv, 0, KTV_B, stream);
  (void)hipMemsetAsync(Pp3, 0, PP_B, stream);
  hipLaunchKernelGGL(wt_kernel, dim3(8, 8, 2), dim3(256), 0, stream, WK, WV, Wt);
  hipLaunchKernelGGL(proj_kernel, dim3(2048), dim3(256), 0, stream,
                     Kin, Vin, Wt, bK, bV, kp, vp);
  hipLaunchKernelGGL(ktv_kernel, dim3(32, 64), dim3(256), 0, stream,
                     kp, vp, pos, lnwK, lnbK, lnwV, lnbV, ktv);
  hipLaunchKernelGGL(sbuild_kernel, dim3(64, 4), dim3(256), 0, stream,
                     ktv, fcW, bQ, St, Pp3);
  hipLaunchKernelGGL(cbuild_kernel, dim3(4, 4, 4), dim3(256), 0, stream,
                     St, WQ, Ct);
  hipLaunchKernelGGL(fuse_kernel, dim3(1024), dim3(256), 0, stream,
                     Q, Ct, pos, Pp3, fcb, (float*)d_out);
}

// Round 12
// 218.894 us; speedup vs baseline: 1.4061x; 1.4061x over previous
//
#include <hip/hip_runtime.h>
#include <hip/hip_bf16.h>

typedef short short8 __attribute__((ext_vector_type(8)));
typedef float f32x4 __attribute__((ext_vector_type(4)));
typedef unsigned int uint4v __attribute__((ext_vector_type(4)));

__device__ __forceinline__ short f2bf(float f) {
  unsigned u = __builtin_bit_cast(unsigned, f);
  u += 0x7fffu + ((u >> 16) & 1u);          // RNE
  return (short)(u >> 16);
}
__device__ __forceinline__ float bf2f(short s) {
  unsigned u = ((unsigned)(unsigned short)s) << 16;
  return __builtin_bit_cast(float, u);
}
__device__ __forceinline__ unsigned pk2(float a, float b) {
  __hip_bfloat162 h = __float22bfloat162_rn(float2{a, b});
  unsigned u;
  __builtin_memcpy(&u, &h, 4);
  return u;
}
__device__ __forceinline__ void gl_lds16(const void* g, void* l) {
  __builtin_amdgcn_global_load_lds(
      (const __attribute__((address_space(1))) unsigned int*)g,
      (__attribute__((address_space(3))) unsigned int*)l, 16, 0, 0);
}
__device__ __forceinline__ short8 cvt8(f32x4 a, f32x4 b) {
  uint4v u;
  u[0] = pk2(a[0], a[1]); u[1] = pk2(a[2], a[3]);
  u[2] = pk2(b[0], b[1]); u[3] = pk2(b[2], b[3]);
  return __builtin_bit_cast(short8, u);
}

// ---------------- W transpose + bf16: Wt[z][n][k], z=0:WK z=1:WV ------------
__global__ __launch_bounds__(256) void wt_kernel(
    const float* __restrict__ WK, const float* __restrict__ WV,
    short* __restrict__ Wt)
{
  const int z = blockIdx.z;
  const float* W = (z == 0) ? WK : WV;
  short* o = Wt + (size_t)z * 512 * 512;
  __shared__ short t[64][65];
  const int k0 = blockIdx.y * 64, n0 = blockIdx.x * 64;
  const int c = threadIdx.x & 63, rb = threadIdx.x >> 6;
#pragma unroll
  for (int p = 0; p < 16; ++p) {
    const int kk = p * 4 + rb;
    t[kk][c] = f2bf(W[(size_t)(k0 + kk) * 512 + n0 + c]);
  }
  __syncthreads();
#pragma unroll
  for (int p = 0; p < 16; ++p) {
    const int nn = p * 4 + rb;
    o[(size_t)(n0 + nn) * 512 + k0 + c] = t[c][nn];
  }
}

// ======= m97 core, A staged as RAW FP32 via gl_lds, cvt at frag-read ========
// proj: K/V projections. grid 2048 = 2z x 256mt x 4ct
__global__ __launch_bounds__(256) void proj_kernel(
    const float* __restrict__ Kin, const float* __restrict__ Vin,
    const short* __restrict__ Wt,
    const float* __restrict__ bK, const float* __restrict__ bV,
    short* __restrict__ kp, short* __restrict__ vp)
{
  const int phys = blockIdx.x;
  const int log_ = (phys & 7) * 256 + (phys >> 3);   // 2048 = 8*256 bijective
  const int z = log_ >> 10;
  const int rem = log_ & 1023;
  const int row0 = (rem >> 2) * 128;
  const int col0 = (rem & 3) * 128;

  const float* X    = z ? Vin : Kin;
  const short* Bsrc = Wt + (size_t)z * 512 * 512;
  const float* bias = z ? bV : bK;
  short* dst        = z ? vp : kp;

  __shared__ float a_lds[2][128 * 32];   // raw fp32 A tile, 32 KB
  __shared__ short b_lds[2][128 * 32];   // bf16 B tile, 16 KB

  const int tid = threadIdx.x;
  const int lane = tid & 63, wv = tid >> 6;
  const int wr = wv >> 1, wc = wv & 1;
  const int fr = lane & 15, fg = lane >> 4;

  // A staging (4 code-issues/tile): row = i*32 + wv*8 + (lane>>3);
  // LDS linear dest; global source granule pre-XOR'd by (row&7) == lane>>3
  const int asrow = wv * 8 + (lane >> 3);
  const int asx = (((lane & 7) ^ (lane >> 3)) * 4);  // float offset in row
  const int adst = (wv * 8) * 32 + lane * 4;         // float index, +i*1024

  // B staging (2 code-issues/tile), R9-proven pattern
  const int bsrow = wv * 16 + (lane >> 2);
  const int bswz = ((lane & 3) ^ (bsrow & 3)) * 8;   // bf16 elem offset
  const int bdst = (wv * 16) * 32 + lane * 8;
  const int bsoff = (fg ^ (fr & 3)) * 8;             // B frag-read slot

  // A frag-read offsets: row r, granules {2fg,2fg+1} XOR (r&7 == fr&7)
  int ao0[4], ao1[4];
#pragma unroll
  for (int mi = 0; mi < 4; ++mi) {
    const int r = wr * 64 + mi * 16 + fr;
    ao0[mi] = r * 32 + (((2 * fg) ^ (fr & 7)) * 4);
    ao1[mi] = r * 32 + (((2 * fg + 1) ^ (fr & 7)) * 4);
  }

  f32x4 acc[4][4];
#pragma unroll
  for (int i = 0; i < 4; ++i)
#pragma unroll
    for (int j = 0; j < 4; ++j) acc[i][j] = (f32x4){0.f, 0.f, 0.f, 0.f};

  // prologue: tile 0 -> buf 0
#pragma unroll
  for (int i = 0; i < 4; ++i)
    gl_lds16(X + (size_t)(row0 + i * 32 + asrow) * 512 + asx,
             &a_lds[0][i * 1024 + adst]);
#pragma unroll
  for (int i = 0; i < 2; ++i)
    gl_lds16(Bsrc + (size_t)(col0 + i * 64 + bsrow) * 512 + bswz,
             &b_lds[0][(i * 64) * 32 + bdst]);
  __syncthreads();

  for (int t = 0; t < 16; ++t) {
    if (t < 15) {                        // prefetch t+1 into other buf
      const int k1 = (t + 1) * 32;
      float* an = a_lds[(t + 1) & 1];
      short* bn = b_lds[(t + 1) & 1];
#pragma unroll
      for (int i = 0; i < 4; ++i)
        gl_lds16(X + (size_t)(row0 + i * 32 + asrow) * 512 + k1 + asx,
                 &an[i * 1024 + adst]);
#pragma unroll
      for (int i = 0; i < 2; ++i)
        gl_lds16(Bsrc + (size_t)(col0 + i * 64 + bsrow) * 512 + k1 + bswz,
                 &bn[(i * 64) * 32 + bdst]);
    }
    const float* ac = a_lds[t & 1];
    const short* bc = b_lds[t & 1];
    short8 af[4], bfv[4];
#pragma unroll
    for (int mi = 0; mi < 4; ++mi) {
      f32x4 lo = *(const f32x4*)&ac[ao0[mi]];
      f32x4 hi = *(const f32x4*)&ac[ao1[mi]];
      af[mi] = cvt8(lo, hi);
    }
#pragma unroll
    for (int ni = 0; ni < 4; ++ni)
      bfv[ni] = *(const short8*)&bc[(wc * 64 + ni * 16 + fr) * 32 + bsoff];
    __builtin_amdgcn_s_setprio(1);
#pragma unroll
    for (int mi = 0; mi < 4; ++mi)
#pragma unroll
      for (int ni = 0; ni < 4; ++ni)
        acc[mi][ni] = __builtin_amdgcn_mfma_f32_16x16x32_bf16(af[mi], bfv[ni], acc[mi][ni], 0, 0, 0);
    __builtin_amdgcn_s_setprio(0);
    __syncthreads();
  }

#pragma unroll
  for (int ni = 0; ni < 4; ++ni) {
    const int gc = col0 + wc * 64 + ni * 16 + fr;
    const float bv = bias[gc];
#pragma unroll
    for (int mi = 0; mi < 4; ++mi) {
#pragma unroll
      for (int r = 0; r < 4; ++r) {
        const int gr = row0 + wr * 64 + mi * 16 + fg * 4 + r;
        dst[(size_t)gr * 512 + gc] = f2bf(acc[mi][ni][r] + bv);
      }
    }
  }
}

// ---------------- LN + ktv accumulation (unchanged) -------------------------
#define SC 256
#define TP 264

__global__ __launch_bounds__(256) void ktv_kernel(
    const short* __restrict__ kp, const short* __restrict__ vp,
    const float* __restrict__ pos,
    const float* __restrict__ lnwK, const float* __restrict__ lnbK,
    const float* __restrict__ lnwV, const float* __restrict__ lnbV,
    float* __restrict__ ktv)
{
  const int nh = blockIdx.y;
  const int n = nh >> 4, h = nh & 15;
  const int s0 = blockIdx.x * SC;
  const int tid = threadIdx.x;

  __shared__ short klds[48 * TP];
  __shared__ short vlds[48 * TP];
  __shared__ float lw[2][32], lb[2][32];

  if (tid < 32) {
    lw[0][tid] = lnwK[h * 32 + tid]; lb[0][tid] = lnbK[h * 32 + tid];
    lw[1][tid] = lnwV[h * 32 + tid]; lb[1][tid] = lnbV[h * 32 + tid];
  }
  __syncthreads();

  const size_t rowix = (size_t)n * 8192 + (s0 + tid);
  {
    const short8* src = (const short8*)(kp + rowix * 512 + h * 32);
    short8 r0 = src[0], r1 = src[1], r2 = src[2], r3 = src[3];
    float x[32];
#pragma unroll
    for (int i = 0; i < 8; ++i) { x[i] = bf2f(r0[i]); x[8+i] = bf2f(r1[i]); x[16+i] = bf2f(r2[i]); x[24+i] = bf2f(r3[i]); }
    float mu = 0.f;
#pragma unroll
    for (int i = 0; i < 32; ++i) mu += x[i];
    mu *= (1.f / 32.f);
    float var = 0.f;
#pragma unroll
    for (int i = 0; i < 32; ++i) { float d = x[i] - mu; var += d * d; }
    var *= (1.f / 32.f);
    const float rstd = rsqrtf(var + 1e-5f);
#pragma unroll
    for (int d = 0; d < 32; ++d)
      klds[d * TP + tid] = f2bf((x[d] - mu) * rstd * lw[0][d] + lb[0][d]);
  }
  {
    const short8* src = (const short8*)(vp + rowix * 512 + h * 32);
    short8 r0 = src[0], r1 = src[1], r2 = src[2], r3 = src[3];
    float x[32];
#pragma unroll
    for (int i = 0; i < 8; ++i) { x[i] = bf2f(r0[i]); x[8+i] = bf2f(r1[i]); x[16+i] = bf2f(r2[i]); x[24+i] = bf2f(r3[i]); }
    float mu = 0.f;
#pragma unroll
    for (int i = 0; i < 32; ++i) mu += x[i];
    mu *= (1.f / 32.f);
    float var = 0.f;
#pragma unroll
    for (int i = 0; i < 32; ++i) { float d = x[i] - mu; var += d * d; }
    var *= (1.f / 32.f);
    const float rstd = rsqrtf(var + 1e-5f);
#pragma unroll
    for (int d = 0; d < 32; ++d)
      vlds[d * TP + tid] = f2bf((x[d] - mu) * rstd * lw[1][d] + lb[1][d]);
  }
  {
    const short p0 = f2bf(pos[rowix * 2]);
    const short p1 = f2bf(pos[rowix * 2 + 1]);
    klds[32 * TP + tid] = p0; klds[33 * TP + tid] = p1;
    vlds[32 * TP + tid] = p0; vlds[33 * TP + tid] = p1;
  }
  __syncthreads();

  const int wv = tid >> 6, lane = tid & 63;
  if (wv < 3) {
    const int fr = lane & 15, fg = lane >> 4;
    f32x4 acc[3];
#pragma unroll
    for (int i = 0; i < 3; ++i) acc[i] = (f32x4){0.f, 0.f, 0.f, 0.f};
    for (int kk = 0; kk < SC; kk += 32) {
      short8 a = *(const short8*)&klds[(wv * 16 + fr) * TP + kk + fg * 8];
#pragma unroll
      for (int ni = 0; ni < 3; ++ni) {
        short8 b = *(const short8*)&vlds[(ni * 16 + fr) * TP + kk + fg * 8];
        acc[ni] = __builtin_amdgcn_mfma_f32_16x16x32_bf16(a, b, acc[ni], 0, 0, 0);
      }
    }
#pragma unroll
    for (int ni = 0; ni < 3; ++ni) {
      const int ei = ni * 16 + fr;
      if (ei < 34) {
        const int er = (ei < 32) ? ei + 2 : ei - 32;
#pragma unroll
        for (int r = 0; r < 4; ++r) {
          const int di = wv * 16 + fg * 4 + r;
          if (di < 34) {
            const int dr = (di < 32) ? di + 2 : di - 32;
            atomicAdd(&ktv[((size_t)nh * 34 + dr) * 34 + er], acc[ni][r]);
          }
        }
      }
    }
  }
}

// ---- S-build (64x4): St[n][o][m] fp32 + Pp3 accumulators -------------------
__global__ __launch_bounds__(256) void sbuild_kernel(
    const float* __restrict__ ktv, const float* __restrict__ fcW,
    const float* __restrict__ bQ, float* __restrict__ St, float* __restrict__ Pp3)
{
  const int nh = blockIdx.x;
  const int n = nh >> 4, h = nh & 15;
  const int jq = blockIdx.y;
  __shared__ float g[34 * 34];
  __shared__ float bq8[8];
  for (int i = threadIdx.x; i < 34 * 34; i += 256)
    g[i] = ktv[(size_t)nh * 34 * 34 + i] * (1.f / 8192.f);
  if (threadIdx.x < 8) bq8[threadIdx.x] = bQ[h * 32 + jq * 8 + threadIdx.x];
  __syncthreads();

  for (int o = threadIdx.x; o < 512; o += 256) {
    float wcol[34];
#pragma unroll
    for (int e = 0; e < 34; ++e) wcol[e] = fcW[(size_t)o * 544 + h * 34 + e];
    float rv = 0.f;
    float* srow = St + ((size_t)n * 512 + o) * 512 + h * 32 + jq * 8;
#pragma unroll
    for (int jj = 0; jj < 8; ++jj) {
      const int j = jq * 8 + jj;
      float s = 0.f;
#pragma unroll
      for (int e = 0; e < 34; ++e) s += g[(j + 2) * 34 + e] * wcol[e];
      srow[jj] = s;
      rv += bq8[jj] * s;
    }
    atomicAdd(&Pp3[((size_t)n * 3 + 2) * 512 + o], rv);
    if (jq == 0) {
      float p0 = 0.f, p1 = 0.f;
#pragma unroll
      for (int e = 0; e < 34; ++e) { p0 += g[e] * wcol[e]; p1 += g[34 + e] * wcol[e]; }
      atomicAdd(&Pp3[((size_t)n * 3 + 0) * 512 + o], p0);
      atomicAdd(&Pp3[((size_t)n * 3 + 1) * 512 + o], p1);
    }
  }
}

// ---- C-build: Ct[n][o][k] = sum_m St[n][o][m] * WQ[k][m], bf16 out ---------
__global__ __launch_bounds__(256) void cbuild_kernel(
    const float* __restrict__ St, const float* __restrict__ WQ,
    short* __restrict__ Ct)
{
  const int n = blockIdx.z;
  const int row0 = blockIdx.y * 128;   // o
  const int col0 = blockIdx.x * 128;   // k
  const float* A = St + (size_t)n * 512 * 512;
  const float* B = WQ;

  __shared__ short a_lds[128 * 32];
  __shared__ short b_lds2[128 * 32];

  const int tid = threadIdx.x;
  const int lane = tid & 63, wv = tid >> 6;
  const int wr = wv >> 1, wc = wv & 1;
  const int fr = lane & 15, fg = lane >> 4;
  const int ar = tid >> 1, ak = (tid & 1) * 16;

  f32x4 acc[4][4];
#pragma unroll
  for (int i = 0; i < 4; ++i)
#pragma unroll
    for (int j = 0; j < 4; ++j) acc[i][j] = (f32x4){0.f, 0.f, 0.f, 0.f};

  for (int k0 = 0; k0 < 512; k0 += 32) {
    __syncthreads();
    {
      const f32x4* ap = (const f32x4*)(A + (size_t)(row0 + ar) * 512 + k0 + ak);
      f32x4 f0 = ap[0], f1 = ap[1], f2 = ap[2], f3 = ap[3];
      uint4v s0, s1;
      s0[0] = pk2(f0[0], f0[1]); s0[1] = pk2(f0[2], f0[3]);
      s0[2] = pk2(f1[0], f1[1]); s0[3] = pk2(f1[2], f1[3]);
      s1[0] = pk2(f2[0], f2[1]); s1[1] = pk2(f2[2], f2[3]);
      s1[2] = pk2(f3[0], f3[1]); s1[3] = pk2(f3[2], f3[3]);
      *(uint4v*)&a_lds[ar * 32 + ak] = s0;
      *(uint4v*)&a_lds[ar * 32 + ak + 8] = s1;
      const f32x4* bp = (const f32x4*)(B + (size_t)(col0 + ar) * 512 + k0 + ak);
      f32x4 g0 = bp[0], g1 = bp[1], g2 = bp[2], g3 = bp[3];
      s0[0] = pk2(g0[0], g0[1]); s0[1] = pk2(g0[2], g0[3]);
      s0[2] = pk2(g1[0], g1[1]); s0[3] = pk2(g1[2], g1[3]);
      s1[0] = pk2(g2[0], g2[1]); s1[1] = pk2(g2[2], g2[3]);
      s1[2] = pk2(g3[0], g3[1]); s1[3] = pk2(g3[2], g3[3]);
      *(uint4v*)&b_lds2[ar * 32 + ak] = s0;
      *(uint4v*)&b_lds2[ar * 32 + ak + 8] = s1;
    }
    __syncthreads();

    short8 af[4], bfr[4];
#pragma unroll
    for (int mi = 0; mi < 4; ++mi)
      af[mi] = *(const short8*)&a_lds[(wr * 64 + mi * 16 + fr) * 32 + fg * 8];
#pragma unroll
    for (int ni = 0; ni < 4; ++ni)
      bfr[ni] = *(const short8*)&b_lds2[(wc * 64 + ni * 16 + fr) * 32 + fg * 8];
#pragma unroll
    for (int mi = 0; mi < 4; ++mi)
#pragma unroll
      for (int ni = 0; ni < 4; ++ni)
        acc[mi][ni] = __builtin_amdgcn_mfma_f32_16x16x32_bf16(af[mi], bfr[ni], acc[mi][ni], 0, 0, 0);
  }

#pragma unroll
  for (int ni = 0; ni < 4; ++ni) {
    const int gc = col0 + wc * 64 + ni * 16 + fr;
#pragma unroll
    for (int mi = 0; mi < 4; ++mi)
#pragma unroll
      for (int r = 0; r < 4; ++r) {
        const int gr = row0 + wr * 64 + mi * 16 + fg * 4 + r;
        Ct[((size_t)n * 512 + gr) * 512 + gc] = f2bf(acc[mi][ni][r]);
      }
  }
}

// ======== fuse: out[n] = Q[n] @ Ct[n]^T + pos terms; same fp32-A core =======
// grid 1024 = 4n x 64mt x 4ct
__global__ __launch_bounds__(256) void fuse_kernel(
    const float* __restrict__ Q, const short* __restrict__ Ct,
    const float* __restrict__ pos, const float* __restrict__ Pp3,
    const float* __restrict__ fcb, float* __restrict__ out)
{
  const int phys = blockIdx.x;
  const int log_ = (phys & 7) * 128 + (phys >> 3);   // 1024 = 8*128
  const int n = log_ >> 8;
  const int rem = log_ & 255;
  const int row0 = (rem >> 2) * 128;
  const int col0 = (rem & 3) * 128;

  const float* X    = Q + (size_t)n * 8192 * 512;
  const short* Bsrc = Ct + (size_t)n * 512 * 512;
  float* dstf       = out + (size_t)n * 8192 * 512;
  const float* posn = pos + (size_t)n * 8192 * 2;

  __shared__ float a_lds[2][128 * 32];
  __shared__ short b_lds[2][128 * 32];

  const int tid = threadIdx.x;
  const int lane = tid & 63, wv = tid >> 6;
  const int wr = wv >> 1, wc = wv & 1;
  const int fr = lane & 15, fg = lane >> 4;

  const int asrow = wv * 8 + (lane >> 3);
  const int asx = (((lane & 7) ^ (lane >> 3)) * 4);
  const int adst = (wv * 8) * 32 + lane * 4;

  const int bsrow = wv * 16 + (lane >> 2);
  const int bswz = ((lane & 3) ^ (bsrow & 3)) * 8;
  const int bdst = (wv * 16) * 32 + lane * 8;
  const int bsoff = (fg ^ (fr & 3)) * 8;

  int ao0[4], ao1[4];
#pragma unroll
  for (int mi = 0; mi < 4; ++mi) {
    const int r = wr * 64 + mi * 16 + fr;
    ao0[mi] = r * 32 + (((2 * fg) ^ (fr & 7)) * 4);
    ao1[mi] = r * 32 + (((2 * fg + 1) ^ (fr & 7)) * 4);
  }

  f32x4 acc[4][4];
#pragma unroll
  for (int i = 0; i < 4; ++i)
#pragma unroll
    for (int j = 0; j < 4; ++j) acc[i][j] = (f32x4){0.f, 0.f, 0.f, 0.f};

#pragma unroll
  for (int i = 0; i < 4; ++i)
    gl_lds16(X + (size_t)(row0 + i * 32 + asrow) * 512 + asx,
             &a_lds[0][i * 1024 + adst]);
#pragma unroll
  for (int i = 0; i < 2; ++i)
    gl_lds16(Bsrc + (size_t)(col0 + i * 64 + bsrow) * 512 + bswz,
             &b_lds[0][(i * 64) * 32 + bdst]);
  __syncthreads();

  for (int t = 0; t < 16; ++t) {
    if (t < 15) {
      const int k1 = (t + 1) * 32;
      float* an = a_lds[(t + 1) & 1];
      short* bn = b_lds[(t + 1) & 1];
#pragma unroll
      for (int i = 0; i < 4; ++i)
        gl_lds16(X + (size_t)(row0 + i * 32 + asrow) * 512 + k1 + asx,
                 &an[i * 1024 + adst]);
#pragma unroll
      for (int i = 0; i < 2; ++i)
        gl_lds16(Bsrc + (size_t)(col0 + i * 64 + bsrow) * 512 + k1 + bswz,
                 &bn[(i * 64) * 32 + bdst]);
    }
    const float* ac = a_lds[t & 1];
    const short* bc = b_lds[t & 1];
    short8 af[4], bfv[4];
#pragma unroll
    for (int mi = 0; mi < 4; ++mi) {
      f32x4 lo = *(const f32x4*)&ac[ao0[mi]];
      f32x4 hi = *(const f32x4*)&ac[ao1[mi]];
      af[mi] = cvt8(lo, hi);
    }
#pragma unroll
    for (int ni = 0; ni < 4; ++ni)
      bfv[ni] = *(const short8*)&bc[(wc * 64 + ni * 16 + fr) * 32 + bsoff];
    __builtin_amdgcn_s_setprio(1);
#pragma unroll
    for (int mi = 0; mi < 4; ++mi)
#pragma unroll
      for (int ni = 0; ni < 4; ++ni)
        acc[mi][ni] = __builtin_amdgcn_mfma_f32_16x16x32_bf16(af[mi], bfv[ni], acc[mi][ni], 0, 0, 0);
    __builtin_amdgcn_s_setprio(0);
    __syncthreads();
  }

  float pp0[4], pp1[4], rv[4];
#pragma unroll
  for (int ni = 0; ni < 4; ++ni) {
    const int gc = col0 + wc * 64 + ni * 16 + fr;
    pp0[ni] = Pp3[((size_t)n * 3 + 0) * 512 + gc];
    pp1[ni] = Pp3[((size_t)n * 3 + 1) * 512 + gc];
    rv[ni]  = Pp3[((size_t)n * 3 + 2) * 512 + gc] + fcb[gc];
  }
#pragma unroll
  for (int mi = 0; mi < 4; ++mi) {
#pragma unroll
    for (int r = 0; r < 4; ++r) {
      const int gr = row0 + wr * 64 + mi * 16 + fg * 4 + r;
      const float q0 = posn[(size_t)gr * 2];
      const float q1 = posn[(size_t)gr * 2 + 1];
#pragma unroll
      for (int ni = 0; ni < 4; ++ni) {
        const int gc = col0 + wc * 64 + ni * 16 + fr;
        dstf[(size_t)gr * 512 + gc] =
            acc[mi][ni][r] + pp0[ni] * q0 + pp1[ni] * q1 + rv[ni];
      }
    }
  }
}

// ---------------------------------------------------------------------------
extern "C" void kernel_launch(void* const* d_in, const int* in_sizes, int n_in,
                              void* d_out, int out_size, void* d_ws, size_t ws_size,
                              hipStream_t stream) {
  const float* Q    = (const float*)d_in[0];
  const float* Kin  = (const float*)d_in[1];
  const float* Vin  = (const float*)d_in[2];
  const float* pos  = (const float*)d_in[3];
  const float* WQ   = (const float*)d_in[4];
  const float* WK   = (const float*)d_in[5];
  const float* WV   = (const float*)d_in[6];
  const float* bQ   = (const float*)d_in[7];
  const float* bK   = (const float*)d_in[8];
  const float* bV   = (const float*)d_in[9];
  const float* lnwK = (const float*)d_in[10];
  const float* lnbK = (const float*)d_in[11];
  const float* lnwV = (const float*)d_in[12];
  const float* lnbV = (const float*)d_in[13];
  const float* fcW  = (const float*)d_in[14];
  const float* fcb  = (const float*)d_in[15];

  char* ws = (char*)d_ws;
  const size_t KP_B  = (size_t)4 * 8192 * 512 * 2;   // 33,554,432
  const size_t KTV_B = (size_t)64 * 34 * 34 * 4;     //    295,936
  const size_t ST_B  = (size_t)4 * 512 * 512 * 4;    //  4,194,304
  const size_t CT_B  = (size_t)4 * 512 * 512 * 2;    //  2,097,152
  const size_t WT_B  = (size_t)2 * 512 * 512 * 2;    //  1,048,576
  const size_t PP_B  = (size_t)4 * 3 * 512 * 4;      //     24,576
  short* kp  = (short*)ws;
  short* vp  = (short*)(ws + KP_B);
  float* ktv = (float*)(ws + 2 * KP_B);
  float* St  = (float*)(ws + 2 * KP_B + KTV_B);
  short* Ct  = (short*)(ws + 2 * KP_B + KTV_B + ST_B);
  short* Wt  = (short*)(ws + 2 * KP_B + KTV_B + ST_B + CT_B);
  float* Pp3 = (float*)(ws + 2 * KP_B + KTV_B + ST_B + CT_B + WT_B);

  (void)hipMemsetAsync(ktv, 0, KTV_B, stream);
  (void)hipMemsetAsync(Pp3, 0, PP_B, stream);
  hipLaunchKernelGGL(wt_kernel, dim3(8, 8, 2), dim3(256), 0, stream, WK, WV, Wt);
  hipLaunchKernelGGL(proj_kernel, dim3(2048), dim3(256), 0, stream,
                     Kin, Vin, Wt, bK, bV, kp, vp);
  hipLaunchKernelGGL(ktv_kernel, dim3(32, 64), dim3(256), 0, stream,
                     kp, vp, pos, lnwK, lnbK, lnwV, lnbV, ktv);
  hipLaunchKernelGGL(sbuild_kernel, dim3(64, 4), dim3(256), 0, stream,
                     ktv, fcW, bQ, St, Pp3);
  hipLaunchKernelGGL(cbuild_kernel, dim3(4, 4, 4), dim3(256), 0, stream,
                     St, WQ, Ct);
  hipLaunchKernelGGL(fuse_kernel, dim3(1024), dim3(256), 0, stream,
                     Q, Ct, pos, Pp3, fcb, (float*)d_out);
}

// Round 13
// 195.855 us; speedup vs baseline: 1.5716x; 1.1176x over previous
//
#include <hip/hip_runtime.h>
#include <hip/hip_bf16.h>

typedef short short8 __attribute__((ext_vector_type(8)));
typedef float f32x4 __attribute__((ext_vector_type(4)));
typedef unsigned int uint4v __attribute__((ext_vector_type(4)));

__device__ __forceinline__ short f2bf(float f) {
  unsigned u = __builtin_bit_cast(unsigned, f);
  u += 0x7fffu + ((u >> 16) & 1u);          // RNE
  return (short)(u >> 16);
}
__device__ __forceinline__ float bf2f(short s) {
  unsigned u = ((unsigned)(unsigned short)s) << 16;
  return __builtin_bit_cast(float, u);
}
__device__ __forceinline__ unsigned pk2(float a, float b) {
  __hip_bfloat162 h = __float22bfloat162_rn(float2{a, b});
  unsigned u;
  __builtin_memcpy(&u, &h, 4);
  return u;
}
__device__ __forceinline__ void gl_lds16(const void* g, void* l) {
  __builtin_amdgcn_global_load_lds(
      (const __attribute__((address_space(1))) unsigned int*)g,
      (__attribute__((address_space(3))) unsigned int*)l, 16, 0, 0);
}
// 16 fp32 (4x f32x4) -> 2x 16B bf16 LDS writes
__device__ __forceinline__ void cvt16(const f32x4* p, short* d0, short* d1) {
  uint4v s;
  s[0] = pk2(p[0][0], p[0][1]); s[1] = pk2(p[0][2], p[0][3]);
  s[2] = pk2(p[1][0], p[1][1]); s[3] = pk2(p[1][2], p[1][3]);
  *(uint4v*)d0 = s;
  s[0] = pk2(p[2][0], p[2][1]); s[1] = pk2(p[2][2], p[2][3]);
  s[2] = pk2(p[3][0], p[3][1]); s[3] = pk2(p[3][2], p[3][3]);
  *(uint4v*)d1 = s;
}

// ---------------- W transpose + bf16: Wt[z][n][k], z=0:WK z=1:WV ------------
__global__ __launch_bounds__(256) void wt_kernel(
    const float* __restrict__ WK, const float* __restrict__ WV,
    short* __restrict__ Wt)
{
  const int z = blockIdx.z;
  const float* W = (z == 0) ? WK : WV;
  short* o = Wt + (size_t)z * 512 * 512;
  __shared__ short t[64][65];
  const int k0 = blockIdx.y * 64, n0 = blockIdx.x * 64;
  const int c = threadIdx.x & 63, rb = threadIdx.x >> 6;
#pragma unroll
  for (int p = 0; p < 16; ++p) {
    const int kk = p * 4 + rb;
    t[kk][c] = f2bf(W[(size_t)(k0 + kk) * 512 + n0 + c]);
  }
  __syncthreads();
#pragma unroll
  for (int p = 0; p < 16; ++p) {
    const int nn = p * 4 + rb;
    o[(size_t)(n0 + nn) * 512 + k0 + c] = t[c][nn];
  }
}

// ============ 8-phase 256x256 K=512 GEMM: K/V projection =====================
// (R8 core, + LDS-staged coalesced C store)
__global__ __launch_bounds__(512, 2) void proj_kernel(
    const float* __restrict__ Kin, const float* __restrict__ Vin,
    const short* __restrict__ Wt,
    const float* __restrict__ bK, const float* __restrict__ bV,
    short* __restrict__ kp, short* __restrict__ vp)
{
  const int phys = blockIdx.x;
  const int log_ = (phys & 7) * 64 + (phys >> 3);     // 512 = 8*64 bijective
  const int z = log_ >> 8;
  const int rem = log_ & 255;
  const int row0 = (rem >> 1) * 256;
  const int col0 = (rem & 1) * 256;

  const float* X    = (z == 0) ? Kin : Vin;
  const float* bias = (z == 0) ? bK  : bV;
  const short* Wz   = Wt + (size_t)z * 512 * 512;
  short* dst        = (z == 0) ? kp : vp;

  __shared__ short POOL[65536];          // 128 KB: staging dbuf, then ctile
#define ABUF(h) (&POOL[(h) * 16384])
#define BBUF(h) (&POOL[32768 + (h) * 16384])

  const int tid = threadIdx.x;
  const int lane = tid & 63, wv = tid >> 6;
  const int wr = wv >> 2, wc = wv & 3;                // wave C tile 128x64
  const int fr = lane & 15, fg = lane >> 4;
  const int sxm = fr & 7;

  // A staging: 4 threads/row, 16 f32 each (row 0..127 per half)
  const int arow = tid >> 2, aseg = tid & 3;
  const float* abase = X + (size_t)(row0 + arow) * 512 + aseg * 16;
  const int awo0 = arow * 64 + (((aseg * 2 + 0) ^ (arow & 7)) * 8);
  const int awo1 = arow * 64 + (((aseg * 2 + 1) ^ (arow & 7)) * 8);

  // B staging: per wave 2 gl_lds per half (8 rows x 8 slots each)
  const int brr = wv * 16 + (lane >> 3);
  const int bso = ((lane & 7) ^ ((lane >> 3) & 7)) * 8;   // pre-swizzled source
  const int bdo = (wv * 16) * 64 + lane * 8;              // linear LDS dest

  f32x4 acc[8][4];
#pragma unroll
  for (int i = 0; i < 8; ++i)
#pragma unroll
    for (int j = 0; j < 4; ++j) acc[i][j] = (f32x4){0.f, 0.f, 0.f, 0.f};

  f32x4 pA0[4], pA1[4];

  // ---- prologue: stage tile 0 -> buf 0
  {
#pragma unroll
    for (int hh = 0; hh < 2; ++hh)
#pragma unroll
      for (int j = 0; j < 2; ++j)
        gl_lds16(Wz + (size_t)(col0 + hh * 128 + brr + j * 8) * 512 + bso,
                 BBUF(0) + bdo + (hh * 128 + j * 8) * 64);
#pragma unroll
    for (int j = 0; j < 4; ++j) pA0[j] = *(const f32x4*)(abase + j * 4);
#pragma unroll
    for (int j = 0; j < 4; ++j) pA1[j] = *(const f32x4*)(abase + (size_t)128 * 512 + j * 4);
    cvt16(pA0, ABUF(0) + awo0, ABUF(0) + awo1);
    cvt16(pA1, ABUF(0) + awo0 + 128 * 64, ABUF(0) + awo1 + 128 * 64);
  }
  asm volatile("s_waitcnt lgkmcnt(0)" ::: "memory");
  __builtin_amdgcn_s_barrier();

  for (int i = 0; i < 4; ++i) {
#pragma unroll
    for (int h = 0; h < 2; ++h) {
      const int st = 2 * i + h + 1;     // tile staged during this half
      const bool dost = (st < 8);
      const int sb = st & 1;            // == h^1
      const short* ab = ABUF(h);
      const short* bb = BBUF(h);
#pragma unroll
      for (int q = 0; q < 4; ++q) {
        // --- phase q: ds_read quadrant of tile (buf h)
        short8 af[2][4], bf[2][2];
#pragma unroll
        for (int kk = 0; kk < 2; ++kk) {
          const int so = (((kk << 2) | fg) ^ sxm) * 8;
#pragma unroll
          for (int ni = 0; ni < 2; ++ni)
            bf[kk][ni] = *(const short8*)&bb[(wc * 64 + (q & 1) * 32 + ni * 16 + fr) * 64 + so];
#pragma unroll
          for (int mi = 0; mi < 4; ++mi)
            af[kk][mi] = *(const short8*)&ab[(wr * 128 + (q >> 1) * 64 + mi * 16 + fr) * 64 + so];
        }
        // --- stage slot for this phase
        bool wrote = false;
        if (dost) {
          if (q == 0) {
#pragma unroll
            for (int hh = 0; hh < 2; ++hh)
#pragma unroll
              for (int j = 0; j < 2; ++j)
                gl_lds16(Wz + (size_t)(col0 + hh * 128 + brr + j * 8) * 512 + st * 64 + bso,
                         BBUF(sb) + bdo + (hh * 128 + j * 8) * 64);
#pragma unroll
            for (int j = 0; j < 4; ++j)
              pA0[j] = *(const f32x4*)(abase + st * 64 + j * 4);
          } else if (q == 1) {
#pragma unroll
            for (int j = 0; j < 4; ++j)
              pA1[j] = *(const f32x4*)(abase + (size_t)128 * 512 + st * 64 + j * 4);
          } else if (q == 2) {
            cvt16(pA0, ABUF(sb) + awo0, ABUF(sb) + awo1);   // auto-vmcnt drains B glds too
            wrote = true;
          } else {
            cvt16(pA1, ABUF(sb) + awo0 + 128 * 64, ABUF(sb) + awo1 + 128 * 64);
            wrote = true;
          }
        }
        if (wrote) asm volatile("s_waitcnt lgkmcnt(0)" ::: "memory");
        __builtin_amdgcn_s_barrier();
        __builtin_amdgcn_s_setprio(1);
#pragma unroll
        for (int kk = 0; kk < 2; ++kk)
#pragma unroll
          for (int mi = 0; mi < 4; ++mi)
#pragma unroll
            for (int ni = 0; ni < 2; ++ni)
              acc[(q >> 1) * 4 + mi][(q & 1) * 2 + ni] =
                  __builtin_amdgcn_mfma_f32_16x16x32_bf16(
                      af[kk][mi], bf[kk][ni], acc[(q >> 1) * 4 + mi][(q & 1) * 2 + ni], 0, 0, 0);
        __builtin_amdgcn_s_setprio(0);
        __builtin_amdgcn_s_barrier();
      }
    }
  }

  // ---- LDS-staged coalesced C store (two column-halves of the 256x256 tile)
  short* ctile = POOL;                   // [256][136], 69.6 KB (pool is dead)
#pragma unroll
  for (int hc = 0; hc < 2; ++hc) {
    __syncthreads();
    if ((wc >> 1) == hc) {
      const int lcb = (wc & 1) * 64;
#pragma unroll
      for (int ni = 0; ni < 4; ++ni) {
        const int gc = col0 + wc * 64 + ni * 16 + fr;
        const float bv = bias[gc];
        const int lc = lcb + ni * 16 + fr;
#pragma unroll
        for (int mi = 0; mi < 8; ++mi)
#pragma unroll
          for (int r = 0; r < 4; ++r) {
            const int row = wr * 128 + mi * 16 + fg * 4 + r;
            ctile[row * 136 + lc] = f2bf(acc[mi][ni][r] + bv);
          }
      }
    }
    __syncthreads();
#pragma unroll
    for (int i = 0; i < 8; ++i) {
      const int c = tid + i * 512;       // 4096 chunks of 16B
      const int row = c >> 4, lcol = (c & 15) * 8;
      uint4v v = *(const uint4v*)&ctile[row * 136 + lcol];
      *(uint4v*)&dst[(size_t)(row0 + row) * 512 + col0 + hc * 128 + lcol] = v;
    }
  }
#undef ABUF
#undef BBUF
}

// ---------------- LN + ktv accumulation (unchanged) -------------------------
#define SC 256
#define TP 264

__global__ __launch_bounds__(256) void ktv_kernel(
    const short* __restrict__ kp, const short* __restrict__ vp,
    const float* __restrict__ pos,
    const float* __restrict__ lnwK, const float* __restrict__ lnbK,
    const float* __restrict__ lnwV, const float* __restrict__ lnbV,
    float* __restrict__ ktv)
{
  const int nh = blockIdx.y;
  const int n = nh >> 4, h = nh & 15;
  const int s0 = blockIdx.x * SC;
  const int tid = threadIdx.x;

  __shared__ short klds[48 * TP];
  __shared__ short vlds[48 * TP];
  __shared__ float lw[2][32], lb[2][32];

  if (tid < 32) {
    lw[0][tid] = lnwK[h * 32 + tid]; lb[0][tid] = lnbK[h * 32 + tid];
    lw[1][tid] = lnwV[h * 32 + tid]; lb[1][tid] = lnbV[h * 32 + tid];
  }
  __syncthreads();

  const size_t rowix = (size_t)n * 8192 + (s0 + tid);
  {
    const short8* src = (const short8*)(kp + rowix * 512 + h * 32);
    short8 r0 = src[0], r1 = src[1], r2 = src[2], r3 = src[3];
    float x[32];
#pragma unroll
    for (int i = 0; i < 8; ++i) { x[i] = bf2f(r0[i]); x[8+i] = bf2f(r1[i]); x[16+i] = bf2f(r2[i]); x[24+i] = bf2f(r3[i]); }
    float mu = 0.f;
#pragma unroll
    for (int i = 0; i < 32; ++i) mu += x[i];
    mu *= (1.f / 32.f);
    float var = 0.f;
#pragma unroll
    for (int i = 0; i < 32; ++i) { float d = x[i] - mu; var += d * d; }
    var *= (1.f / 32.f);
    const float rstd = rsqrtf(var + 1e-5f);
#pragma unroll
    for (int d = 0; d < 32; ++d)
      klds[d * TP + tid] = f2bf((x[d] - mu) * rstd * lw[0][d] + lb[0][d]);
  }
  {
    const short8* src = (const short8*)(vp + rowix * 512 + h * 32);
    short8 r0 = src[0], r1 = src[1], r2 = src[2], r3 = src[3];
    float x[32];
#pragma unroll
    for (int i = 0; i < 8; ++i) { x[i] = bf2f(r0[i]); x[8+i] = bf2f(r1[i]); x[16+i] = bf2f(r2[i]); x[24+i] = bf2f(r3[i]); }
    float mu = 0.f;
#pragma unroll
    for (int i = 0; i < 32; ++i) mu += x[i];
    mu *= (1.f / 32.f);
    float var = 0.f;
#pragma unroll
    for (int i = 0; i < 32; ++i) { float d = x[i] - mu; var += d * d; }
    var *= (1.f / 32.f);
    const float rstd = rsqrtf(var + 1e-5f);
#pragma unroll
    for (int d = 0; d < 32; ++d)
      vlds[d * TP + tid] = f2bf((x[d] - mu) * rstd * lw[1][d] + lb[1][d]);
  }
  {
    const short p0 = f2bf(pos[rowix * 2]);
    const short p1 = f2bf(pos[rowix * 2 + 1]);
    klds[32 * TP + tid] = p0; klds[33 * TP + tid] = p1;
    vlds[32 * TP + tid] = p0; vlds[33 * TP + tid] = p1;
  }
  __syncthreads();

  const int wv = tid >> 6, lane = tid & 63;
  if (wv < 3) {
    const int fr = lane & 15, fg = lane >> 4;
    f32x4 acc[3];
#pragma unroll
    for (int i = 0; i < 3; ++i) acc[i] = (f32x4){0.f, 0.f, 0.f, 0.f};
    for (int kk = 0; kk < SC; kk += 32) {
      short8 a = *(const short8*)&klds[(wv * 16 + fr) * TP + kk + fg * 8];
#pragma unroll
      for (int ni = 0; ni < 3; ++ni) {
        short8 b = *(const short8*)&vlds[(ni * 16 + fr) * TP + kk + fg * 8];
        acc[ni] = __builtin_amdgcn_mfma_f32_16x16x32_bf16(a, b, acc[ni], 0, 0, 0);
      }
    }
#pragma unroll
    for (int ni = 0; ni < 3; ++ni) {
      const int ei = ni * 16 + fr;
      if (ei < 34) {
        const int er = (ei < 32) ? ei + 2 : ei - 32;
#pragma unroll
        for (int r = 0; r < 4; ++r) {
          const int di = wv * 16 + fg * 4 + r;
          if (di < 34) {
            const int dr = (di < 32) ? di + 2 : di - 32;
            atomicAdd(&ktv[((size_t)nh * 34 + dr) * 34 + er], acc[ni][r]);
          }
        }
      }
    }
  }
}

// ---- S-build (regridded 64x4): St[n][o][m] fp32 + Pp3 accumulators ---------
__global__ __launch_bounds__(256) void sbuild_kernel(
    const float* __restrict__ ktv, const float* __restrict__ fcW,
    const float* __restrict__ bQ, float* __restrict__ St, float* __restrict__ Pp3)
{
  const int nh = blockIdx.x;
  const int n = nh >> 4, h = nh & 15;
  const int jq = blockIdx.y;            // 0..3 (8 j's each)
  __shared__ float g[34 * 34];
  __shared__ float bq8[8];
  for (int i = threadIdx.x; i < 34 * 34; i += 256)
    g[i] = ktv[(size_t)nh * 34 * 34 + i] * (1.f / 8192.f);
  if (threadIdx.x < 8) bq8[threadIdx.x] = bQ[h * 32 + jq * 8 + threadIdx.x];
  __syncthreads();

  for (int o = threadIdx.x; o < 512; o += 256) {
    float wcol[34];
#pragma unroll
    for (int e = 0; e < 34; ++e) wcol[e] = fcW[(size_t)o * 544 + h * 34 + e];
    float rv = 0.f;
    float* srow = St + ((size_t)n * 512 + o) * 512 + h * 32 + jq * 8;
#pragma unroll
    for (int jj = 0; jj < 8; ++jj) {
      const int j = jq * 8 + jj;
      float s = 0.f;
#pragma unroll
      for (int e = 0; e < 34; ++e) s += g[(j + 2) * 34 + e] * wcol[e];
      srow[jj] = s;
      rv += bq8[jj] * s;
    }
    atomicAdd(&Pp3[((size_t)n * 3 + 2) * 512 + o], rv);
    if (jq == 0) {
      float p0 = 0.f, p1 = 0.f;
#pragma unroll
      for (int e = 0; e < 34; ++e) { p0 += g[e] * wcol[e]; p1 += g[34 + e] * wcol[e]; }
      atomicAdd(&Pp3[((size_t)n * 3 + 0) * 512 + o], p0);
      atomicAdd(&Pp3[((size_t)n * 3 + 1) * 512 + o], p1);
    }
  }
}

// ---- C-build: Ct[n][o][k] = sum_m St[n][o][m] * WQ[k][m], bf16 out ---------
__global__ __launch_bounds__(256) void cbuild_kernel(
    const float* __restrict__ St, const float* __restrict__ WQ,
    short* __restrict__ Ct)
{
  const int n = blockIdx.z;
  const int row0 = blockIdx.y * 128;   // o
  const int col0 = blockIdx.x * 128;   // k
  const float* A = St + (size_t)n * 512 * 512;
  const float* B = WQ;

  __shared__ short a_lds[128 * 32];
  __shared__ short b_lds2[128 * 32];

  const int tid = threadIdx.x;
  const int lane = tid & 63, wv = tid >> 6;
  const int wr = wv >> 1, wc = wv & 1;
  const int fr = lane & 15, fg = lane >> 4;
  const int ar = tid >> 1, ak = (tid & 1) * 16;

  f32x4 acc[4][4];
#pragma unroll
  for (int i = 0; i < 4; ++i)
#pragma unroll
    for (int j = 0; j < 4; ++j) acc[i][j] = (f32x4){0.f, 0.f, 0.f, 0.f};

  for (int k0 = 0; k0 < 512; k0 += 32) {
    __syncthreads();
    {
      const f32x4* ap = (const f32x4*)(A + (size_t)(row0 + ar) * 512 + k0 + ak);
      f32x4 f0 = ap[0], f1 = ap[1], f2 = ap[2], f3 = ap[3];
      uint4v s0, s1;
      s0[0] = pk2(f0[0], f0[1]); s0[1] = pk2(f0[2], f0[3]);
      s0[2] = pk2(f1[0], f1[1]); s0[3] = pk2(f1[2], f1[3]);
      s1[0] = pk2(f2[0], f2[1]); s1[1] = pk2(f2[2], f2[3]);
      s1[2] = pk2(f3[0], f3[1]); s1[3] = pk2(f3[2], f3[3]);
      *(uint4v*)&a_lds[ar * 32 + ak] = s0;
      *(uint4v*)&a_lds[ar * 32 + ak + 8] = s1;
      const f32x4* bp = (const f32x4*)(B + (size_t)(col0 + ar) * 512 + k0 + ak);
      f32x4 g0 = bp[0], g1 = bp[1], g2 = bp[2], g3 = bp[3];
      s0[0] = pk2(g0[0], g0[1]); s0[1] = pk2(g0[2], g0[3]);
      s0[2] = pk2(g1[0], g1[1]); s0[3] = pk2(g1[2], g1[3]);
      s1[0] = pk2(g2[0], g2[1]); s1[1] = pk2(g2[2], g2[3]);
      s1[2] = pk2(g3[0], g3[1]); s1[3] = pk2(g3[2], g3[3]);
      *(uint4v*)&b_lds2[ar * 32 + ak] = s0;
      *(uint4v*)&b_lds2[ar * 32 + ak + 8] = s1;
    }
    __syncthreads();

    short8 af[4], bfr[4];
#pragma unroll
    for (int mi = 0; mi < 4; ++mi)
      af[mi] = *(const short8*)&a_lds[(wr * 64 + mi * 16 + fr) * 32 + fg * 8];
#pragma unroll
    for (int ni = 0; ni < 4; ++ni)
      bfr[ni] = *(const short8*)&b_lds2[(wc * 64 + ni * 16 + fr) * 32 + fg * 8];
#pragma unroll
    for (int mi = 0; mi < 4; ++mi)
#pragma unroll
      for (int ni = 0; ni < 4; ++ni)
        acc[mi][ni] = __builtin_amdgcn_mfma_f32_16x16x32_bf16(af[mi], bfr[ni], acc[mi][ni], 0, 0, 0);
  }

#pragma unroll
  for (int ni = 0; ni < 4; ++ni) {
    const int gc = col0 + wc * 64 + ni * 16 + fr;
#pragma unroll
    for (int mi = 0; mi < 4; ++mi)
#pragma unroll
      for (int r = 0; r < 4; ++r) {
        const int gr = row0 + wr * 64 + mi * 16 + fg * 4 + r;
        Ct[((size_t)n * 512 + gr) * 512 + gc] = f2bf(acc[mi][ni][r]);
      }
  }
}

// ============ 8-phase fused final GEMM: out = Q@C + pos terms ================
__global__ __launch_bounds__(512, 2) void fuse_kernel(
    const float* __restrict__ Q, const short* __restrict__ Ct,
    const float* __restrict__ pos, const float* __restrict__ Pp3,
    const float* __restrict__ fcb, float* __restrict__ out)
{
  const int phys = blockIdx.x;
  const int log_ = (phys & 7) * 32 + (phys >> 3);     // 256 = 8*32
  const int n = log_ >> 6;
  const int rem = log_ & 63;
  const int row0 = (rem >> 1) * 256;
  const int col0 = (rem & 1) * 256;

  const float* X = Q + (size_t)n * 8192 * 512;
  const short* Bz = Ct + (size_t)n * 512 * 512;

  __shared__ short a_lds[2][256 * 64];
  __shared__ short b_lds[2][256 * 64];

  const int tid = threadIdx.x;
  const int lane = tid & 63, wv = tid >> 6;
  const int wr = wv >> 2, wc = wv & 3;
  const int fr = lane & 15, fg = lane >> 4;
  const int sxm = fr & 7;

  const int arow = tid >> 2, aseg = tid & 3;
  const float* abase = X + (size_t)(row0 + arow) * 512 + aseg * 16;
  const int awo0 = arow * 64 + (((aseg * 2 + 0) ^ (arow & 7)) * 8);
  const int awo1 = arow * 64 + (((aseg * 2 + 1) ^ (arow & 7)) * 8);

  const int brr = wv * 16 + (lane >> 3);
  const int bso = ((lane & 7) ^ ((lane >> 3) & 7)) * 8;
  const int bdo = (wv * 16) * 64 + lane * 8;

  f32x4 acc[8][4];
#pragma unroll
  for (int i = 0; i < 8; ++i)
#pragma unroll
    for (int j = 0; j < 4; ++j) acc[i][j] = (f32x4){0.f, 0.f, 0.f, 0.f};

  f32x4 pA0[4], pA1[4];

  {
#pragma unroll
    for (int hh = 0; hh < 2; ++hh)
#pragma unroll
      for (int j = 0; j < 2; ++j)
        gl_lds16(Bz + (size_t)(col0 + hh * 128 + brr + j * 8) * 512 + bso,
                 &b_lds[0][bdo + (hh * 128 + j * 8) * 64]);
#pragma unroll
    for (int j = 0; j < 4; ++j) pA0[j] = *(const f32x4*)(abase + j * 4);
#pragma unroll
    for (int j = 0; j < 4; ++j) pA1[j] = *(const f32x4*)(abase + (size_t)128 * 512 + j * 4);
    cvt16(pA0, &a_lds[0][awo0], &a_lds[0][awo1]);
    cvt16(pA1, &a_lds[0][awo0 + 128 * 64], &a_lds[0][awo1 + 128 * 64]);
  }
  asm volatile("s_waitcnt lgkmcnt(0)" ::: "memory");
  __builtin_amdgcn_s_barrier();

  for (int i = 0; i < 4; ++i) {
#pragma unroll
    for (int h = 0; h < 2; ++h) {
      const int st = 2 * i + h + 1;
      const bool dost = (st < 8);
      const int sb = st & 1;
      const short* ab = &a_lds[h][0];
      const short* bb = &b_lds[h][0];
#pragma unroll
      for (int q = 0; q < 4; ++q) {
        short8 af[2][4], bf[2][2];
#pragma unroll
        for (int kk = 0; kk < 2; ++kk) {
          const int so = (((kk << 2) | fg) ^ sxm) * 8;
#pragma unroll
          for (int ni = 0; ni < 2; ++ni)
            bf[kk][ni] = *(const short8*)&bb[(wc * 64 + (q & 1) * 32 + ni * 16 + fr) * 64 + so];
#pragma unroll
          for (int mi = 0; mi < 4; ++mi)
            af[kk][mi] = *(const short8*)&ab[(wr * 128 + (q >> 1) * 64 + mi * 16 + fr) * 64 + so];
        }
        bool wrote = false;
        if (dost) {
          if (q == 0) {
#pragma unroll
            for (int hh = 0; hh < 2; ++hh)
#pragma unroll
              for (int j = 0; j < 2; ++j)
                gl_lds16(Bz + (size_t)(col0 + hh * 128 + brr + j * 8) * 512 + st * 64 + bso,
                         &b_lds[sb][bdo + (hh * 128 + j * 8) * 64]);
#pragma unroll
            for (int j = 0; j < 4; ++j)
              pA0[j] = *(const f32x4*)(abase + st * 64 + j * 4);
          } else if (q == 1) {
#pragma unroll
            for (int j = 0; j < 4; ++j)
              pA1[j] = *(const f32x4*)(abase + (size_t)128 * 512 + st * 64 + j * 4);
          } else if (q == 2) {
            cvt16(pA0, &a_lds[sb][awo0], &a_lds[sb][awo1]);
            wrote = true;
          } else {
            cvt16(pA1, &a_lds[sb][awo0 + 128 * 64], &a_lds[sb][awo1 + 128 * 64]);
            wrote = true;
          }
        }
        if (wrote) asm volatile("s_waitcnt lgkmcnt(0)" ::: "memory");
        __builtin_amdgcn_s_barrier();
        __builtin_amdgcn_s_setprio(1);
#pragma unroll
        for (int kk = 0; kk < 2; ++kk)
#pragma unroll
          for (int mi = 0; mi < 4; ++mi)
#pragma unroll
            for (int ni = 0; ni < 2; ++ni)
              acc[(q >> 1) * 4 + mi][(q & 1) * 2 + ni] =
                  __builtin_amdgcn_mfma_f32_16x16x32_bf16(
                      af[kk][mi], bf[kk][ni], acc[(q >> 1) * 4 + mi][(q & 1) * 2 + ni], 0, 0, 0);
        __builtin_amdgcn_s_setprio(0);
        __builtin_amdgcn_s_barrier();
      }
    }
  }

  // epilogue: + pos-term + bQ-term + fc_b
  float pp0[4], pp1[4], rv[4];
#pragma unroll
  for (int ni = 0; ni < 4; ++ni) {
    const int gc = col0 + wc * 64 + ni * 16 + fr;
    pp0[ni] = Pp3[((size_t)n * 3 + 0) * 512 + gc];
    pp1[ni] = Pp3[((size_t)n * 3 + 1) * 512 + gc];
    rv[ni]  = Pp3[((size_t)n * 3 + 2) * 512 + gc] + fcb[gc];
  }
#pragma unroll
  for (int mi = 0; mi < 8; ++mi) {
#pragma unroll
    for (int r = 0; r < 4; ++r) {
      const int gr = row0 + wr * 128 + mi * 16 + fg * 4 + r;
      const float* pr = pos + ((size_t)n * 8192 + gr) * 2;
      const float q0 = pr[0], q1 = pr[1];
#pragma unroll
      for (int ni = 0; ni < 4; ++ni) {
        const int gc = col0 + wc * 64 + ni * 16 + fr;
        out[((size_t)n * 8192 + gr) * 512 + gc] =
            acc[mi][ni][r] + pp0[ni] * q0 + pp1[ni] * q1 + rv[ni];
      }
    }
  }
}

// ---------------------------------------------------------------------------
extern "C" void kernel_launch(void* const* d_in, const int* in_sizes, int n_in,
                              void* d_out, int out_size, void* d_ws, size_t ws_size,
                              hipStream_t stream) {
  const float* Q    = (const float*)d_in[0];
  const float* Kin  = (const float*)d_in[1];
  const float* Vin  = (const float*)d_in[2];
  const float* pos  = (const float*)d_in[3];
  const float* WQ   = (const float*)d_in[4];
  const float* WK   = (const float*)d_in[5];
  const float* WV   = (const float*)d_in[6];
  const float* bQ   = (const float*)d_in[7];
  const float* bK   = (const float*)d_in[8];
  const float* bV   = (const float*)d_in[9];
  const float* lnwK = (const float*)d_in[10];
  const float* lnbK = (const float*)d_in[11];
  const float* lnwV = (const float*)d_in[12];
  const float* lnbV = (const float*)d_in[13];
  const float* fcW  = (const float*)d_in[14];
  const float* fcb  = (const float*)d_in[15];

  char* ws = (char*)d_ws;
  const size_t KP_B  = (size_t)4 * 8192 * 512 * 2;   // 33,554,432
  const size_t KTV_B = (size_t)64 * 34 * 34 * 4;     //    295,936
  const size_t ST_B  = (size_t)4 * 512 * 512 * 4;    //  4,194,304
  const size_t CT_B  = (size_t)4 * 512 * 512 * 2;    //  2,097,152
  const size_t WT_B  = (size_t)2 * 512 * 512 * 2;    //  1,048,576
  const size_t PP_B  = (size_t)4 * 3 * 512 * 4;      //     24,576
  short* kp  = (short*)ws;
  short* vp  = (short*)(ws + KP_B);
  float* ktv = (float*)(ws + 2 * KP_B);
  float* St  = (float*)(ws + 2 * KP_B + KTV_B);
  short* Ct  = (short*)(ws + 2 * KP_B + KTV_B + ST_B);
  short* Wt  = (short*)(ws + 2 * KP_B + KTV_B + ST_B + CT_B);
  float* Pp3 = (float*)(ws + 2 * KP_B + KTV_B + ST_B + CT_B + WT_B);

  (void)hipMemsetAsync(ktv, 0, KTV_B, stream);
  (void)hipMemsetAsync(Pp3, 0, PP_B, stream);
  hipLaunchKernelGGL(wt_kernel, dim3(8, 8, 2), dim3(256), 0, stream, WK, WV, Wt);
  hipLaunchKernelGGL(proj_kernel, dim3(512), dim3(512), 0, stream,
                     Kin, Vin, Wt, bK, bV, kp, vp);
  hipLaunchKernelGGL(ktv_kernel, dim3(32, 64), dim3(256), 0, stream,
                     kp, vp, pos, lnwK, lnbK, lnwV, lnbV, ktv);
  hipLaunchKernelGGL(sbuild_kernel, dim3(64, 4), dim3(256), 0, stream,
                     ktv, fcW, bQ, St, Pp3);
  hipLaunchKernelGGL(cbuild_kernel, dim3(4, 4, 4), dim3(256), 0, stream,
                     St, WQ, Ct);
  hipLaunchKernelGGL(fuse_kernel, dim3(256), dim3(512), 0, stream,
                     Q, Ct, pos, Pp3, fcb, (float*)d_out);
}

// Round 14
// 190.221 us; speedup vs baseline: 1.6181x; 1.0296x over previous
//
#include <hip/hip_runtime.h>
#include <hip/hip_bf16.h>

typedef short short8 __attribute__((ext_vector_type(8)));
typedef float f32x4 __attribute__((ext_vector_type(4)));
typedef unsigned int uint4v __attribute__((ext_vector_type(4)));

__device__ __forceinline__ short f2bf(float f) {
  unsigned u = __builtin_bit_cast(unsigned, f);
  u += 0x7fffu + ((u >> 16) & 1u);          // RNE
  return (short)(u >> 16);
}
__device__ __forceinline__ float bf2f(short s) {
  unsigned u = ((unsigned)(unsigned short)s) << 16;
  return __builtin_bit_cast(float, u);
}
__device__ __forceinline__ unsigned pk2(float a, float b) {
  __hip_bfloat162 h = __float22bfloat162_rn(float2{a, b});
  unsigned u;
  __builtin_memcpy(&u, &h, 4);
  return u;
}
__device__ __forceinline__ void gl_lds16(const void* g, void* l) {
  __builtin_amdgcn_global_load_lds(
      (const __attribute__((address_space(1))) unsigned int*)g,
      (__attribute__((address_space(3))) unsigned int*)l, 16, 0, 0);
}
// 16 fp32 (4x f32x4) -> 2x 16B bf16 LDS writes
__device__ __forceinline__ void cvt16(const f32x4* p, short* d0, short* d1) {
  uint4v s;
  s[0] = pk2(p[0][0], p[0][1]); s[1] = pk2(p[0][2], p[0][3]);
  s[2] = pk2(p[1][0], p[1][1]); s[3] = pk2(p[1][2], p[1][3]);
  *(uint4v*)d0 = s;
  s[0] = pk2(p[2][0], p[2][1]); s[1] = pk2(p[2][2], p[2][3]);
  s[2] = pk2(p[3][0], p[3][1]); s[3] = pk2(p[3][2], p[3][3]);
  *(uint4v*)d1 = s;
}

// ---------------- W transpose + bf16: Wt[z][n][k], z=0:WK z=1:WV ------------
__global__ __launch_bounds__(256) void wt_kernel(
    const float* __restrict__ WK, const float* __restrict__ WV,
    short* __restrict__ Wt)
{
  const int z = blockIdx.z;
  const float* W = (z == 0) ? WK : WV;
  short* o = Wt + (size_t)z * 512 * 512;
  __shared__ short t[64][65];
  const int k0 = blockIdx.y * 64, n0 = blockIdx.x * 64;
  const int c = threadIdx.x & 63, rb = threadIdx.x >> 6;
#pragma unroll
  for (int p = 0; p < 16; ++p) {
    const int kk = p * 4 + rb;
    t[kk][c] = f2bf(W[(size_t)(k0 + kk) * 512 + n0 + c]);
  }
  __syncthreads();
#pragma unroll
  for (int p = 0; p < 16; ++p) {
    const int nn = p * 4 + rb;
    o[(size_t)(n0 + nn) * 512 + k0 + c] = t[c][nn];
  }
}

// ============ 8-phase 256x256 K=512 GEMM: K/V projection =====================
// (R13 core: 8-phase + LDS-staged coalesced C store)
__global__ __launch_bounds__(512, 2) void proj_kernel(
    const float* __restrict__ Kin, const float* __restrict__ Vin,
    const short* __restrict__ Wt,
    const float* __restrict__ bK, const float* __restrict__ bV,
    short* __restrict__ kp, short* __restrict__ vp)
{
  const int phys = blockIdx.x;
  const int log_ = (phys & 7) * 64 + (phys >> 3);     // 512 = 8*64 bijective
  const int z = log_ >> 8;
  const int rem = log_ & 255;
  const int row0 = (rem >> 1) * 256;
  const int col0 = (rem & 1) * 256;

  const float* X    = (z == 0) ? Kin : Vin;
  const float* bias = (z == 0) ? bK  : bV;
  const short* Wz   = Wt + (size_t)z * 512 * 512;
  short* dst        = (z == 0) ? kp : vp;

  __shared__ short POOL[65536];          // 128 KB: staging dbuf, then ctile
#define ABUF(h) (&POOL[(h) * 16384])
#define BBUF(h) (&POOL[32768 + (h) * 16384])

  const int tid = threadIdx.x;
  const int lane = tid & 63, wv = tid >> 6;
  const int wr = wv >> 2, wc = wv & 3;                // wave C tile 128x64
  const int fr = lane & 15, fg = lane >> 4;
  const int sxm = fr & 7;

  const int arow = tid >> 2, aseg = tid & 3;
  const float* abase = X + (size_t)(row0 + arow) * 512 + aseg * 16;
  const int awo0 = arow * 64 + (((aseg * 2 + 0) ^ (arow & 7)) * 8);
  const int awo1 = arow * 64 + (((aseg * 2 + 1) ^ (arow & 7)) * 8);

  const int brr = wv * 16 + (lane >> 3);
  const int bso = ((lane & 7) ^ ((lane >> 3) & 7)) * 8;   // pre-swizzled source
  const int bdo = (wv * 16) * 64 + lane * 8;              // linear LDS dest

  f32x4 acc[8][4];
#pragma unroll
  for (int i = 0; i < 8; ++i)
#pragma unroll
    for (int j = 0; j < 4; ++j) acc[i][j] = (f32x4){0.f, 0.f, 0.f, 0.f};

  f32x4 pA0[4], pA1[4];

  {
#pragma unroll
    for (int hh = 0; hh < 2; ++hh)
#pragma unroll
      for (int j = 0; j < 2; ++j)
        gl_lds16(Wz + (size_t)(col0 + hh * 128 + brr + j * 8) * 512 + bso,
                 BBUF(0) + bdo + (hh * 128 + j * 8) * 64);
#pragma unroll
    for (int j = 0; j < 4; ++j) pA0[j] = *(const f32x4*)(abase + j * 4);
#pragma unroll
    for (int j = 0; j < 4; ++j) pA1[j] = *(const f32x4*)(abase + (size_t)128 * 512 + j * 4);
    cvt16(pA0, ABUF(0) + awo0, ABUF(0) + awo1);
    cvt16(pA1, ABUF(0) + awo0 + 128 * 64, ABUF(0) + awo1 + 128 * 64);
  }
  asm volatile("s_waitcnt lgkmcnt(0)" ::: "memory");
  __builtin_amdgcn_s_barrier();

  for (int i = 0; i < 4; ++i) {
#pragma unroll
    for (int h = 0; h < 2; ++h) {
      const int st = 2 * i + h + 1;
      const bool dost = (st < 8);
      const int sb = st & 1;
      const short* ab = ABUF(h);
      const short* bb = BBUF(h);
#pragma unroll
      for (int q = 0; q < 4; ++q) {
        short8 af[2][4], bf[2][2];
#pragma unroll
        for (int kk = 0; kk < 2; ++kk) {
          const int so = (((kk << 2) | fg) ^ sxm) * 8;
#pragma unroll
          for (int ni = 0; ni < 2; ++ni)
            bf[kk][ni] = *(const short8*)&bb[(wc * 64 + (q & 1) * 32 + ni * 16 + fr) * 64 + so];
#pragma unroll
          for (int mi = 0; mi < 4; ++mi)
            af[kk][mi] = *(const short8*)&ab[(wr * 128 + (q >> 1) * 64 + mi * 16 + fr) * 64 + so];
        }
        bool wrote = false;
        if (dost) {
          if (q == 0) {
#pragma unroll
            for (int hh = 0; hh < 2; ++hh)
#pragma unroll
              for (int j = 0; j < 2; ++j)
                gl_lds16(Wz + (size_t)(col0 + hh * 128 + brr + j * 8) * 512 + st * 64 + bso,
                         BBUF(sb) + bdo + (hh * 128 + j * 8) * 64);
#pragma unroll
            for (int j = 0; j < 4; ++j)
              pA0[j] = *(const f32x4*)(abase + st * 64 + j * 4);
          } else if (q == 1) {
#pragma unroll
            for (int j = 0; j < 4; ++j)
              pA1[j] = *(const f32x4*)(abase + (size_t)128 * 512 + st * 64 + j * 4);
          } else if (q == 2) {
            cvt16(pA0, ABUF(sb) + awo0, ABUF(sb) + awo1);
            wrote = true;
          } else {
            cvt16(pA1, ABUF(sb) + awo0 + 128 * 64, ABUF(sb) + awo1 + 128 * 64);
            wrote = true;
          }
        }
        if (wrote) asm volatile("s_waitcnt lgkmcnt(0)" ::: "memory");
        __builtin_amdgcn_s_barrier();
        __builtin_amdgcn_s_setprio(1);
#pragma unroll
        for (int kk = 0; kk < 2; ++kk)
#pragma unroll
          for (int mi = 0; mi < 4; ++mi)
#pragma unroll
            for (int ni = 0; ni < 2; ++ni)
              acc[(q >> 1) * 4 + mi][(q & 1) * 2 + ni] =
                  __builtin_amdgcn_mfma_f32_16x16x32_bf16(
                      af[kk][mi], bf[kk][ni], acc[(q >> 1) * 4 + mi][(q & 1) * 2 + ni], 0, 0, 0);
        __builtin_amdgcn_s_setprio(0);
        __builtin_amdgcn_s_barrier();
      }
    }
  }

  // ---- LDS-staged coalesced C store (two column-halves of the 256x256 tile)
  short* ctile = POOL;                   // [256][136]
#pragma unroll
  for (int hc = 0; hc < 2; ++hc) {
    __syncthreads();
    if ((wc >> 1) == hc) {
      const int lcb = (wc & 1) * 64;
#pragma unroll
      for (int ni = 0; ni < 4; ++ni) {
        const int gc = col0 + wc * 64 + ni * 16 + fr;
        const float bv = bias[gc];
        const int lc = lcb + ni * 16 + fr;
#pragma unroll
        for (int mi = 0; mi < 8; ++mi)
#pragma unroll
          for (int r = 0; r < 4; ++r) {
            const int row = wr * 128 + mi * 16 + fg * 4 + r;
            ctile[row * 136 + lc] = f2bf(acc[mi][ni][r] + bv);
          }
      }
    }
    __syncthreads();
#pragma unroll
    for (int i = 0; i < 8; ++i) {
      const int c = tid + i * 512;
      const int row = c >> 4, lcol = (c & 15) * 8;
      uint4v v = *(const uint4v*)&ctile[row * 136 + lcol];
      *(uint4v*)&dst[(size_t)(row0 + row) * 512 + col0 + hc * 128 + lcol] = v;
    }
  }
#undef ABUF
#undef BBUF
}

// ---------------- LN + ktv accumulation (XCD-chunked 1D grid) ---------------
#define SC 256
#define TP 264

__global__ __launch_bounds__(256) void ktv_kernel(
    const short* __restrict__ kp, const short* __restrict__ vp,
    const float* __restrict__ pos,
    const float* __restrict__ lnwK, const float* __restrict__ lnbK,
    const float* __restrict__ lnwV, const float* __restrict__ lnbV,
    float* __restrict__ ktv)
{
  // 2048 blocks; chunked swizzle: each XCD gets 256 consecutive logical blocks
  // logical = rowgroup*16 + h  -> all 16 heads of a rowgroup on one XCD (L2 reuse)
  const int phys = blockIdx.x;
  const int log_ = (phys & 7) * 256 + (phys >> 3);
  const int grp = log_ >> 4;            // 0..127 row-groups
  const int h = log_ & 15;
  const int n = grp >> 5;
  const int s0 = (grp & 31) * SC;
  const int nh = n * 16 + h;
  const int tid = threadIdx.x;

  __shared__ short klds[48 * TP];
  __shared__ short vlds[48 * TP];
  __shared__ float lw[2][32], lb[2][32];

  if (tid < 32) {
    lw[0][tid] = lnwK[h * 32 + tid]; lb[0][tid] = lnbK[h * 32 + tid];
    lw[1][tid] = lnwV[h * 32 + tid]; lb[1][tid] = lnbV[h * 32 + tid];
  }
  __syncthreads();

  const size_t rowix = (size_t)n * 8192 + (s0 + tid);
  {
    const short8* src = (const short8*)(kp + rowix * 512 + h * 32);
    short8 r0 = src[0], r1 = src[1], r2 = src[2], r3 = src[3];
    float x[32];
#pragma unroll
    for (int i = 0; i < 8; ++i) { x[i] = bf2f(r0[i]); x[8+i] = bf2f(r1[i]); x[16+i] = bf2f(r2[i]); x[24+i] = bf2f(r3[i]); }
    float mu = 0.f;
#pragma unroll
    for (int i = 0; i < 32; ++i) mu += x[i];
    mu *= (1.f / 32.f);
    float var = 0.f;
#pragma unroll
    for (int i = 0; i < 32; ++i) { float d = x[i] - mu; var += d * d; }
    var *= (1.f / 32.f);
    const float rstd = rsqrtf(var + 1e-5f);
#pragma unroll
    for (int d = 0; d < 32; ++d)
      klds[d * TP + tid] = f2bf((x[d] - mu) * rstd * lw[0][d] + lb[0][d]);
  }
  {
    const short8* src = (const short8*)(vp + rowix * 512 + h * 32);
    short8 r0 = src[0], r1 = src[1], r2 = src[2], r3 = src[3];
    float x[32];
#pragma unroll
    for (int i = 0; i < 8; ++i) { x[i] = bf2f(r0[i]); x[8+i] = bf2f(r1[i]); x[16+i] = bf2f(r2[i]); x[24+i] = bf2f(r3[i]); }
    float mu = 0.f;
#pragma unroll
    for (int i = 0; i < 32; ++i) mu += x[i];
    mu *= (1.f / 32.f);
    float var = 0.f;
#pragma unroll
    for (int i = 0; i < 32; ++i) { float d = x[i] - mu; var += d * d; }
    var *= (1.f / 32.f);
    const float rstd = rsqrtf(var + 1e-5f);
#pragma unroll
    for (int d = 0; d < 32; ++d)
      vlds[d * TP + tid] = f2bf((x[d] - mu) * rstd * lw[1][d] + lb[1][d]);
  }
  {
    const short p0 = f2bf(pos[rowix * 2]);
    const short p1 = f2bf(pos[rowix * 2 + 1]);
    klds[32 * TP + tid] = p0; klds[33 * TP + tid] = p1;
    vlds[32 * TP + tid] = p0; vlds[33 * TP + tid] = p1;
  }
  __syncthreads();

  const int wv = tid >> 6, lane = tid & 63;
  if (wv < 3) {
    const int fr = lane & 15, fg = lane >> 4;
    f32x4 acc[3];
#pragma unroll
    for (int i = 0; i < 3; ++i) acc[i] = (f32x4){0.f, 0.f, 0.f, 0.f};
    for (int kk = 0; kk < SC; kk += 32) {
      short8 a = *(const short8*)&klds[(wv * 16 + fr) * TP + kk + fg * 8];
#pragma unroll
      for (int ni = 0; ni < 3; ++ni) {
        short8 b = *(const short8*)&vlds[(ni * 16 + fr) * TP + kk + fg * 8];
        acc[ni] = __builtin_amdgcn_mfma_f32_16x16x32_bf16(a, b, acc[ni], 0, 0, 0);
      }
    }
#pragma unroll
    for (int ni = 0; ni < 3; ++ni) {
      const int ei = ni * 16 + fr;
      if (ei < 34) {
        const int er = (ei < 32) ? ei + 2 : ei - 32;
#pragma unroll
        for (int r = 0; r < 4; ++r) {
          const int di = wv * 16 + fg * 4 + r;
          if (di < 34) {
            const int dr = (di < 32) ? di + 2 : di - 32;
            atomicAdd(&ktv[((size_t)nh * 34 + dr) * 34 + er], acc[ni][r]);
          }
        }
      }
    }
  }
}

// ---- S-build (64x4): St[n][o][m] fp32 + Pp3 accumulators -------------------
__global__ __launch_bounds__(256) void sbuild_kernel(
    const float* __restrict__ ktv, const float* __restrict__ fcW,
    const float* __restrict__ bQ, float* __restrict__ St, float* __restrict__ Pp3)
{
  const int nh = blockIdx.x;
  const int n = nh >> 4, h = nh & 15;
  const int jq = blockIdx.y;
  __shared__ float g[34 * 34];
  __shared__ float bq8[8];
  for (int i = threadIdx.x; i < 34 * 34; i += 256)
    g[i] = ktv[(size_t)nh * 34 * 34 + i] * (1.f / 8192.f);
  if (threadIdx.x < 8) bq8[threadIdx.x] = bQ[h * 32 + jq * 8 + threadIdx.x];
  __syncthreads();

  for (int o = threadIdx.x; o < 512; o += 256) {
    float wcol[34];
#pragma unroll
    for (int e = 0; e < 34; ++e) wcol[e] = fcW[(size_t)o * 544 + h * 34 + e];
    float rv = 0.f;
    float* srow = St + ((size_t)n * 512 + o) * 512 + h * 32 + jq * 8;
#pragma unroll
    for (int jj = 0; jj < 8; ++jj) {
      const int j = jq * 8 + jj;
      float s = 0.f;
#pragma unroll
      for (int e = 0; e < 34; ++e) s += g[(j + 2) * 34 + e] * wcol[e];
      srow[jj] = s;
      rv += bq8[jj] * s;
    }
    atomicAdd(&Pp3[((size_t)n * 3 + 2) * 512 + o], rv);
    if (jq == 0) {
      float p0 = 0.f, p1 = 0.f;
#pragma unroll
      for (int e = 0; e < 34; ++e) { p0 += g[e] * wcol[e]; p1 += g[34 + e] * wcol[e]; }
      atomicAdd(&Pp3[((size_t)n * 3 + 0) * 512 + o], p0);
      atomicAdd(&Pp3[((size_t)n * 3 + 1) * 512 + o], p1);
    }
  }
}

// ---- C-build: Ct[n][o][k] = sum_m St[n][o][m] * WQ[k][m], bf16 out ---------
__global__ __launch_bounds__(256) void cbuild_kernel(
    const float* __restrict__ St, const float* __restrict__ WQ,
    short* __restrict__ Ct)
{
  const int n = blockIdx.z;
  const int row0 = blockIdx.y * 128;   // o
  const int col0 = blockIdx.x * 128;   // k
  const float* A = St + (size_t)n * 512 * 512;
  const float* B = WQ;

  __shared__ short a_lds[128 * 32];
  __shared__ short b_lds2[128 * 32];

  const int tid = threadIdx.x;
  const int lane = tid & 63, wv = tid >> 6;
  const int wr = wv >> 1, wc = wv & 1;
  const int fr = lane & 15, fg = lane >> 4;
  const int ar = tid >> 1, ak = (tid & 1) * 16;

  f32x4 acc[4][4];
#pragma unroll
  for (int i = 0; i < 4; ++i)
#pragma unroll
    for (int j = 0; j < 4; ++j) acc[i][j] = (f32x4){0.f, 0.f, 0.f, 0.f};

  for (int k0 = 0; k0 < 512; k0 += 32) {
    __syncthreads();
    {
      const f32x4* ap = (const f32x4*)(A + (size_t)(row0 + ar) * 512 + k0 + ak);
      f32x4 f0 = ap[0], f1 = ap[1], f2 = ap[2], f3 = ap[3];
      uint4v s0, s1;
      s0[0] = pk2(f0[0], f0[1]); s0[1] = pk2(f0[2], f0[3]);
      s0[2] = pk2(f1[0], f1[1]); s0[3] = pk2(f1[2], f1[3]);
      s1[0] = pk2(f2[0], f2[1]); s1[1] = pk2(f2[2], f2[3]);
      s1[2] = pk2(f3[0], f3[1]); s1[3] = pk2(f3[2], f3[3]);
      *(uint4v*)&a_lds[ar * 32 + ak] = s0;
      *(uint4v*)&a_lds[ar * 32 + ak + 8] = s1;
      const f32x4* bp = (const f32x4*)(B + (size_t)(col0 + ar) * 512 + k0 + ak);
      f32x4 g0 = bp[0], g1 = bp[1], g2 = bp[2], g3 = bp[3];
      s0[0] = pk2(g0[0], g0[1]); s0[1] = pk2(g0[2], g0[3]);
      s0[2] = pk2(g1[0], g1[1]); s0[3] = pk2(g1[2], g1[3]);
      s1[0] = pk2(g2[0], g2[1]); s1[1] = pk2(g2[2], g2[3]);
      s1[2] = pk2(g3[0], g3[1]); s1[3] = pk2(g3[2], g3[3]);
      *(uint4v*)&b_lds2[ar * 32 + ak] = s0;
      *(uint4v*)&b_lds2[ar * 32 + ak + 8] = s1;
    }
    __syncthreads();

    short8 af[4], bfr[4];
#pragma unroll
    for (int mi = 0; mi < 4; ++mi)
      af[mi] = *(const short8*)&a_lds[(wr * 64 + mi * 16 + fr) * 32 + fg * 8];
#pragma unroll
    for (int ni = 0; ni < 4; ++ni)
      bfr[ni] = *(const short8*)&b_lds2[(wc * 64 + ni * 16 + fr) * 32 + fg * 8];
#pragma unroll
    for (int mi = 0; mi < 4; ++mi)
#pragma unroll
      for (int ni = 0; ni < 4; ++ni)
        acc[mi][ni] = __builtin_amdgcn_mfma_f32_16x16x32_bf16(af[mi], bfr[ni], acc[mi][ni], 0, 0, 0);
  }

#pragma unroll
  for (int ni = 0; ni < 4; ++ni) {
    const int gc = col0 + wc * 64 + ni * 16 + fr;
#pragma unroll
    for (int mi = 0; mi < 4; ++mi)
#pragma unroll
      for (int r = 0; r < 4; ++r) {
        const int gr = row0 + wr * 64 + mi * 16 + fg * 4 + r;
        Ct[((size_t)n * 512 + gr) * 512 + gc] = f2bf(acc[mi][ni][r]);
      }
  }
}

// ============ 8-phase fused final GEMM: out = Q@C + pos terms ================
__global__ __launch_bounds__(512, 2) void fuse_kernel(
    const float* __restrict__ Q, const short* __restrict__ Ct,
    const float* __restrict__ pos, const float* __restrict__ Pp3,
    const float* __restrict__ fcb, float* __restrict__ out)
{
  const int phys = blockIdx.x;
  const int log_ = (phys & 7) * 32 + (phys >> 3);     // 256 = 8*32
  const int n = log_ >> 6;
  const int rem = log_ & 63;
  const int row0 = (rem >> 1) * 256;
  const int col0 = (rem & 1) * 256;

  const float* X = Q + (size_t)n * 8192 * 512;
  const short* Bz = Ct + (size_t)n * 512 * 512;

  __shared__ short a_lds[2][256 * 64];
  __shared__ short b_lds[2][256 * 64];

  const int tid = threadIdx.x;
  const int lane = tid & 63, wv = tid >> 6;
  const int wr = wv >> 2, wc = wv & 3;
  const int fr = lane & 15, fg = lane >> 4;
  const int sxm = fr & 7;

  const int arow = tid >> 2, aseg = tid & 3;
  const float* abase = X + (size_t)(row0 + arow) * 512 + aseg * 16;
  const int awo0 = arow * 64 + (((aseg * 2 + 0) ^ (arow & 7)) * 8);
  const int awo1 = arow * 64 + (((aseg * 2 + 1) ^ (arow & 7)) * 8);

  const int brr = wv * 16 + (lane >> 3);
  const int bso = ((lane & 7) ^ ((lane >> 3) & 7)) * 8;
  const int bdo = (wv * 16) * 64 + lane * 8;

  f32x4 acc[8][4];
#pragma unroll
  for (int i = 0; i < 8; ++i)
#pragma unroll
    for (int j = 0; j < 4; ++j) acc[i][j] = (f32x4){0.f, 0.f, 0.f, 0.f};

  f32x4 pA0[4], pA1[4];

  {
#pragma unroll
    for (int hh = 0; hh < 2; ++hh)
#pragma unroll
      for (int j = 0; j < 2; ++j)
        gl_lds16(Bz + (size_t)(col0 + hh * 128 + brr + j * 8) * 512 + bso,
                 &b_lds[0][bdo + (hh * 128 + j * 8) * 64]);
#pragma unroll
    for (int j = 0; j < 4; ++j) pA0[j] = *(const f32x4*)(abase + j * 4);
#pragma unroll
    for (int j = 0; j < 4; ++j) pA1[j] = *(const f32x4*)(abase + (size_t)128 * 512 + j * 4);
    cvt16(pA0, &a_lds[0][awo0], &a_lds[0][awo1]);
    cvt16(pA1, &a_lds[0][awo0 + 128 * 64], &a_lds[0][awo1 + 128 * 64]);
  }
  asm volatile("s_waitcnt lgkmcnt(0)" ::: "memory");
  __builtin_amdgcn_s_barrier();

  for (int i = 0; i < 4; ++i) {
#pragma unroll
    for (int h = 0; h < 2; ++h) {
      const int st = 2 * i + h + 1;
      const bool dost = (st < 8);
      const int sb = st & 1;
      const short* ab = &a_lds[h][0];
      const short* bb = &b_lds[h][0];
#pragma unroll
      for (int q = 0; q < 4; ++q) {
        short8 af[2][4], bf[2][2];
#pragma unroll
        for (int kk = 0; kk < 2; ++kk) {
          const int so = (((kk << 2) | fg) ^ sxm) * 8;
#pragma unroll
          for (int ni = 0; ni < 2; ++ni)
            bf[kk][ni] = *(const short8*)&bb[(wc * 64 + (q & 1) * 32 + ni * 16 + fr) * 64 + so];
#pragma unroll
          for (int mi = 0; mi < 4; ++mi)
            af[kk][mi] = *(const short8*)&ab[(wr * 128 + (q >> 1) * 64 + mi * 16 + fr) * 64 + so];
        }
        bool wrote = false;
        if (dost) {
          if (q == 0) {
#pragma unroll
            for (int hh = 0; hh < 2; ++hh)
#pragma unroll
              for (int j = 0; j < 2; ++j)
                gl_lds16(Bz + (size_t)(col0 + hh * 128 + brr + j * 8) * 512 + st * 64 + bso,
                         &b_lds[sb][bdo + (hh * 128 + j * 8) * 64]);
#pragma unroll
            for (int j = 0; j < 4; ++j)
              pA0[j] = *(const f32x4*)(abase + st * 64 + j * 4);
          } else if (q == 1) {
#pragma unroll
            for (int j = 0; j < 4; ++j)
              pA1[j] = *(const f32x4*)(abase + (size_t)128 * 512 + st * 64 + j * 4);
          } else if (q == 2) {
            cvt16(pA0, &a_lds[sb][awo0], &a_lds[sb][awo1]);
            wrote = true;
          } else {
            cvt16(pA1, &a_lds[sb][awo0 + 128 * 64], &a_lds[sb][awo1 + 128 * 64]);
            wrote = true;
          }
        }
        if (wrote) asm volatile("s_waitcnt lgkmcnt(0)" ::: "memory");
        __builtin_amdgcn_s_barrier();
        __builtin_amdgcn_s_setprio(1);
#pragma unroll
        for (int kk = 0; kk < 2; ++kk)
#pragma unroll
          for (int mi = 0; mi < 4; ++mi)
#pragma unroll
            for (int ni = 0; ni < 2; ++ni)
              acc[(q >> 1) * 4 + mi][(q & 1) * 2 + ni] =
                  __builtin_amdgcn_mfma_f32_16x16x32_bf16(
                      af[kk][mi], bf[kk][ni], acc[(q >> 1) * 4 + mi][(q & 1) * 2 + ni], 0, 0, 0);
        __builtin_amdgcn_s_setprio(0);
        __builtin_amdgcn_s_barrier();
      }
    }
  }

  float pp0[4], pp1[4], rv[4];
#pragma unroll
  for (int ni = 0; ni < 4; ++ni) {
    const int gc = col0 + wc * 64 + ni * 16 + fr;
    pp0[ni] = Pp3[((size_t)n * 3 + 0) * 512 + gc];
    pp1[ni] = Pp3[((size_t)n * 3 + 1) * 512 + gc];
    rv[ni]  = Pp3[((size_t)n * 3 + 2) * 512 + gc] + fcb[gc];
  }
#pragma unroll
  for (int mi = 0; mi < 8; ++mi) {
#pragma unroll
    for (int r = 0; r < 4; ++r) {
      const int gr = row0 + wr * 128 + mi * 16 + fg * 4 + r;
      const float* pr = pos + ((size_t)n * 8192 + gr) * 2;
      const float q0 = pr[0], q1 = pr[1];
#pragma unroll
      for (int ni = 0; ni < 4; ++ni) {
        const int gc = col0 + wc * 64 + ni * 16 + fr;
        out[((size_t)n * 8192 + gr) * 512 + gc] =
            acc[mi][ni][r] + pp0[ni] * q0 + pp1[ni] * q1 + rv[ni];
      }
    }
  }
}

// ---------------------------------------------------------------------------
extern "C" void kernel_launch(void* const* d_in, const int* in_sizes, int n_in,
                              void* d_out, int out_size, void* d_ws, size_t ws_size,
                              hipStream_t stream) {
  const float* Q    = (const float*)d_in[0];
  const float* Kin  = (const float*)d_in[1];
  const float* Vin  = (const float*)d_in[2];
  const float* pos  = (const float*)d_in[3];
  const float* WQ   = (const float*)d_in[4];
  const float* WK   = (const float*)d_in[5];
  const float* WV   = (const float*)d_in[6];
  const float* bQ   = (const float*)d_in[7];
  const float* bK   = (const float*)d_in[8];
  const float* bV   = (const float*)d_in[9];
  const float* lnwK = (const float*)d_in[10];
  const float* lnbK = (const float*)d_in[11];
  const float* lnwV = (const float*)d_in[12];
  const float* lnbV = (const float*)d_in[13];
  const float* fcW  = (const float*)d_in[14];
  const float* fcb  = (const float*)d_in[15];

  char* ws = (char*)d_ws;
  const size_t KP_B  = (size_t)4 * 8192 * 512 * 2;   // 33,554,432
  const size_t KTV_B = (size_t)64 * 34 * 34 * 4;     //    295,936
  const size_t PP_B  = (size_t)4 * 3 * 512 * 4;      //     24,576
  const size_t ST_B  = (size_t)4 * 512 * 512 * 4;    //  4,194,304
  const size_t CT_B  = (size_t)4 * 512 * 512 * 2;    //  2,097,152
  short* kp  = (short*)ws;
  short* vp  = (short*)(ws + KP_B);
  float* ktv = (float*)(ws + 2 * KP_B);                      // ktv+Pp3 adjacent
  float* Pp3 = (float*)(ws + 2 * KP_B + KTV_B);
  float* St  = (float*)(ws + 2 * KP_B + KTV_B + PP_B);
  short* Ct  = (short*)(ws + 2 * KP_B + KTV_B + PP_B + ST_B);
  short* Wt  = (short*)(ws + 2 * KP_B + KTV_B + PP_B + ST_B + CT_B);

  (void)hipMemsetAsync(ktv, 0, KTV_B + PP_B, stream);   // one memset for both
  hipLaunchKernelGGL(wt_kernel, dim3(8, 8, 2), dim3(256), 0, stream, WK, WV, Wt);
  hipLaunchKernelGGL(proj_kernel, dim3(512), dim3(512), 0, stream,
                     Kin, Vin, Wt, bK, bV, kp, vp);
  hipLaunchKernelGGL(ktv_kernel, dim3(2048), dim3(256), 0, stream,
                     kp, vp, pos, lnwK, lnbK, lnwV, lnbV, ktv);
  hipLaunchKernelGGL(sbuild_kernel, dim3(64, 4), dim3(256), 0, stream,
                     ktv, fcW, bQ, St, Pp3);
  hipLaunchKernelGGL(cbuild_kernel, dim3(4, 4, 4), dim3(256), 0, stream,
                     St, WQ, Ct);
  hipLaunchKernelGGL(fuse_kernel, dim3(256), dim3(512), 0, stream,
                     Q, Ct, pos, Pp3, fcb, (float*)d_out);
}